// Round 3
// baseline (1899.071 us; speedup 1.0000x reference)
//
#include <hip/hip_runtime.h>
#include <math.h>

#define NPG 75
#define KDIM 5

__device__ __forceinline__ float eluf(float v){ return v > 0.f ? v : expf(v) - 1.f; }

// order-preserving float <-> uint encoding (for atomicMax-based segment max)
__device__ __forceinline__ unsigned fenc(float f){
    unsigned u = __float_as_uint(f);
    return (u & 0x80000000u) ? ~u : (u | 0x80000000u);
}
__device__ __forceinline__ float fdec(unsigned u){
    return (u & 0x80000000u) ? __uint_as_float(u & 0x7FFFFFFFu) : __uint_as_float(~u);
}

// spline basis: pseudo = cart/(2*amax)+0.5, clip[0,1], *4; 4 corner weights + kernel ids
__device__ __forceinline__ void spline2(float c0, float c1, float am, int* kks, float* wsp){
    float denom = 2.f * fmaxf(am, 1e-12f);
    float p0 = c0 / denom + 0.5f;
    float p1 = c1 / denom + 0.5f;
    p0 = fminf(fmaxf(p0, 0.f), 1.f) * 4.f;
    p1 = fminf(fmaxf(p1, 0.f), 1.f) * 4.f;
    float b0 = fminf(floorf(p0), 3.f);
    float b1 = fminf(floorf(p1), 3.f);
    float f0 = p0 - b0, f1 = p1 - b1;
    int i0 = (int)b0, i1 = (int)b1;
    wsp[0] = (1.f - f0) * (1.f - f1); kks[0] = i0     + KDIM *  i1;
    wsp[1] =        f0  * (1.f - f1); kks[1] = i0 + 1 + KDIM *  i1;
    wsp[2] = (1.f - f0) *        f1 ; kks[2] = i0     + KDIM * (i1 + 1);
    wsp[3] =        f0  *        f1 ; kks[3] = i0 + 1 + KDIM * (i1 + 1);
}

// ---------------- amax over |pos[src]-pos[dst]| (all edges) ----------------
__global__ void amax0_k(const float* __restrict__ pos, const int* __restrict__ src,
                        const int* __restrict__ dst, int E, unsigned* __restrict__ amax){
    int e = blockIdx.x * 256 + threadIdx.x;
    float cand = 0.f;
    if (e < E){
        int s = src[e], d = dst[e];
        float c0 = pos[s*2]   - pos[d*2];
        float c1 = pos[s*2+1] - pos[d*2+1];
        cand = fmaxf(fabsf(c0), fabsf(c1));
    }
    __shared__ float sm[256];
    sm[threadIdx.x] = cand; __syncthreads();
    for (int o = 128; o > 0; o >>= 1){
        if (threadIdx.x < o) sm[threadIdx.x] = fmaxf(sm[threadIdx.x], sm[threadIdx.x + o]);
        __syncthreads();
    }
    if (threadIdx.x == 0 && sm[0] > 0.f) atomicMax(amax, __float_as_uint(sm[0]));
}

// ---------------- conv1: aggregate (Fin=1) ----------------
__global__ void conv1_edge_k(const float* __restrict__ x, const float* __restrict__ pos,
                             const int* __restrict__ src, const int* __restrict__ dst, int E,
                             const unsigned* __restrict__ amaxp,
                             float* __restrict__ acc, float* __restrict__ deg){
    int e = blockIdx.x * 256 + threadIdx.x;
    if (e >= E) return;
    int s = src[e], d = dst[e];
    float am = __uint_as_float(*amaxp);
    float c0 = pos[s*2]   - pos[d*2];
    float c1 = pos[s*2+1] - pos[d*2+1];
    int kks[4]; float wsp[4];
    spline2(c0, c1, am, kks, wsp);
    float xv = x[s];
    #pragma unroll
    for (int c = 0; c < 4; c++) atomicAdd(&acc[(size_t)d*25 + kks[c]], wsp[c] * xv);
    atomicAdd(&deg[d], 1.f);
}

__global__ void conv1_node_k(const float* __restrict__ acc, const float* __restrict__ deg,
                             const float* __restrict__ x, const float* __restrict__ W1,
                             const float* __restrict__ r1, const float* __restrict__ b1,
                             int N, float* __restrict__ out){
    int gid = blockIdx.x * 256 + threadIdx.x;
    int i = gid >> 5, o = gid & 31;
    if (i >= N) return;
    float sum = 0.f;
    #pragma unroll
    for (int k = 0; k < 25; k++) sum += acc[(size_t)i*25 + k] * W1[k*32 + o];
    float v = sum / fmaxf(deg[i], 1.f) + x[i] * r1[o] + b1[o];
    out[(size_t)i*32 + o] = eluf(v);
}

// ---------------- generic pooling ----------------
template<int LOGF>
__global__ void pool_node_k(const float* __restrict__ x, const float* __restrict__ pos,
                            const float* __restrict__ valid, int n, float size, int G, int npg,
                            int* __restrict__ cl, unsigned* __restrict__ pxenc,
                            float* __restrict__ cnt, float* __restrict__ possum){
    const int F = 1 << LOGF;
    int gid = blockIdx.x * 256 + threadIdx.x;
    int i = gid >> LOGF, f = gid & (F - 1);
    if (i >= n) return;
    float p0 = pos[i*2], p1 = pos[i*2+1];
    int c0 = min(max((int)floorf(p0 / size), 0), G - 1);
    int c1 = min(max((int)floorf(p1 / size), 0), G - 1);
    int b = i / npg;
    int c = b * G * G + c1 * G + c0;
    if (f == 0) cl[i] = c;
    float vld = valid ? valid[i] : 1.f;
    if (vld > 0.f){
        atomicMax(&pxenc[(size_t)c*F + f], fenc(x[(size_t)i*F + f]));
        if (f == 0){
            atomicAdd(&cnt[c], 1.f);
            atomicAdd(&possum[c*2],     p0);
            atomicAdd(&possum[c*2 + 1], p1);
        }
    }
}

template<int LOGF>
__global__ void pool_fin_k(unsigned* __restrict__ pxenc, const float* __restrict__ cnt,
                           float* __restrict__ possum, float* __restrict__ sval, int S){
    const int F = 1 << LOGF;
    int gid = blockIdx.x * 256 + threadIdx.x;
    int s = gid >> LOGF, f = gid & (F - 1);
    if (s >= S) return;
    float c = cnt[s];
    float v = (c > 0.f) ? fdec(pxenc[(size_t)s*F + f]) : 0.f;
    ((float*)pxenc)[(size_t)s*F + f] = v;
    if (f == 0){
        float m = fmaxf(c, 1.f);
        possum[s*2]     /= m;
        possum[s*2 + 1] /= m;
        sval[s] = (c > 0.f) ? 1.f : 0.f;
    }
}

// ---------------- edge remap + dedup ----------------
__global__ void dedup_a_k(const int* __restrict__ esrc_in, const int* __restrict__ edst_in,
                          const int* __restrict__ clmap, const unsigned char* __restrict__ maskin,
                          int E, int GG, int* __restrict__ esrc_out, int* __restrict__ edst_out,
                          unsigned* __restrict__ pairmark){
    int e = blockIdx.x * 256 + threadIdx.x;
    if (e >= E) return;
    int a = clmap[esrc_in[e]], b = clmap[edst_in[e]];
    esrc_out[e] = a; edst_out[e] = b;
    bool m = (maskin ? (maskin[e] != 0) : true) && (a != b);
    if (m){
        int g = a / GG;
        unsigned key = (unsigned)((size_t)g * GG * GG + (a - g * GG) * GG + (b - g * GG));
        atomicMin(&pairmark[key], (unsigned)e);
    }
}

__global__ void dedup_b_k(const int* __restrict__ esrc, const int* __restrict__ edst,
                          const unsigned char* __restrict__ maskin, const unsigned* __restrict__ pairmark,
                          const float* __restrict__ ppos, int E, int GG,
                          unsigned char* __restrict__ kf, float* __restrict__ deg,
                          unsigned* __restrict__ amax){
    int e = blockIdx.x * 256 + threadIdx.x;
    float cand = 0.f;
    if (e < E){
        int a = esrc[e], b = edst[e];
        bool m = (maskin ? (maskin[e] != 0) : true) && (a != b);
        bool kept = false;
        if (m){
            int g = a / GG;
            unsigned key = (unsigned)((size_t)g * GG * GG + (a - g * GG) * GG + (b - g * GG));
            kept = (pairmark[key] == (unsigned)e);
        }
        kf[e] = kept ? 1 : 0;
        if (kept){
            float c0 = ppos[a*2]   - ppos[b*2];
            float c1 = ppos[a*2+1] - ppos[b*2+1];
            cand = fmaxf(fabsf(c0), fabsf(c1));
            atomicAdd(&deg[b], 1.f);
        }
    }
    __shared__ float sm[256];
    sm[threadIdx.x] = cand; __syncthreads();
    for (int o = 128; o > 0; o >>= 1){
        if (threadIdx.x < o) sm[threadIdx.x] = fmaxf(sm[threadIdx.x], sm[threadIdx.x + o]);
        __syncthreads();
    }
    if (threadIdx.x == 0 && sm[0] > 0.f) atomicMax(amax, __float_as_uint(sm[0]));
}

// ---------------- CSR build: exclusive scan of deg + fill ----------------
__global__ void scan_k(const float* __restrict__ deg, int n,
                       int* __restrict__ rowptr, int* __restrict__ cursor){
    __shared__ int wt[16];
    __shared__ int wo[17];
    __shared__ int carry;
    int t = threadIdx.x, lane = t & 63, wid = t >> 6;
    if (t == 0) carry = 0;
    __syncthreads();
    for (int base = 0; base < n; base += 1024){
        int i = base + t;
        int v = (i < n) ? (int)deg[i] : 0;
        int incl = v;
        #pragma unroll
        for (int o = 1; o < 64; o <<= 1){
            int u = __shfl_up(incl, o, 64);
            if (lane >= o) incl += u;
        }
        if (lane == 63) wt[wid] = incl;
        __syncthreads();
        if (t == 0){
            int run = 0;
            #pragma unroll
            for (int wv = 0; wv < 16; wv++){ wo[wv] = run; run += wt[wv]; }
            wo[16] = run;
        }
        __syncthreads();
        int ex = incl - v + wo[wid] + carry;
        if (i < n){ rowptr[i] = ex; cursor[i] = ex; }
        __syncthreads();
        if (t == 0) carry += wo[16];
        __syncthreads();
    }
    if (t == 0) rowptr[n] = carry;
}

__global__ void csr_fill_k(const unsigned char* __restrict__ kf, const int* __restrict__ edst,
                           int E, int* __restrict__ cursor, int* __restrict__ elist){
    int e = blockIdx.x * 256 + threadIdx.x;
    if (e >= E) return;
    if (!kf[e]) return;
    int idx = atomicAdd(&cursor[edst[e]], 1);
    elist[idx] = e;
}

// ---------------- conv2/conv3 phase A: CSR gather into LDS, dump acc rows to global ----------------
// 4 dst-nodes per 256-block, 64 lanes per node. acc[25][FIN] per node in LDS.
// FIN=32: two edges per iteration (half-wave each) into two separate buffers (no LDS race).
template<int FIN>
__global__ __launch_bounds__(256) void conv_gather_k(
        const float* __restrict__ x, const float* __restrict__ ppos,
        const int* __restrict__ esrc, const int* __restrict__ elist,
        const int* __restrict__ rowptr, const unsigned* __restrict__ amaxp,
        int n, float* __restrict__ Aout){
    constexpr int EPB = (FIN == 32) ? 2 : 1;
    constexpr int ACC = 25 * FIN;
    __shared__ float acc[4 * EPB * ACC];           // 25.6 KB
    int g = threadIdx.x >> 6, lane = threadIdx.x & 63;
    int node = blockIdx.x * 4 + g;
    float* accg = acc + g * EPB * ACC;

    for (int i = threadIdx.x; i < 4 * EPB * ACC; i += 256) acc[i] = 0.f;
    __syncthreads();

    if (node < n){
        int row0 = rowptr[node], row1 = rowptr[node + 1];
        float am = __uint_as_float(*amaxp);
        float pd0 = ppos[node*2], pd1 = ppos[node*2 + 1];
        int ebuf = (EPB == 2) ? (lane >> 5) : 0;
        int f = lane & (FIN - 1);
        float* ab = accg + ebuf * ACC;
        for (int i = row0 + ebuf; i < row1; i += EPB){
            int e = elist[i];
            int a = esrc[e];
            float c0 = ppos[a*2]     - pd0;
            float c1 = ppos[a*2 + 1] - pd1;
            int kks[4]; float wsp[4];
            spline2(c0, c1, am, kks, wsp);
            float xv = x[(size_t)a * FIN + f];
            #pragma unroll
            for (int c = 0; c < 4; c++) ab[kks[c] * FIN + f] += wsp[c] * xv;
        }
    }
    __syncthreads();

    if (node >= n) return;
    // writeout: per-lane-different float4 LDS reads + coalesced dwordx4 stores
    float4* dst4 = (float4*)(Aout + (size_t)node * ACC);
    const float4* s4  = (const float4*)accg;
    const float4* s4b = (const float4*)(accg + ACC);
    #pragma unroll 2
    for (int j = lane; j < ACC / 4; j += 64){
        float4 v = s4[j];
        if (EPB == 2){
            float4 u = s4b[j];
            v.x += u.x; v.y += u.y; v.z += u.z; v.w += u.w;
        }
        dst4[j] = v;
    }
}

// ---------------- conv2/conv3 phase B: row-streaming fp32 GEMM + fused epilogue ----------------
// wave = 64 outputs (lane = o) x 16 rows; W chunk (32 x 64) lives in VGPRs, reused
// across the 16 rows; A rows streamed as wave-uniform float4 loads (scalar path).
template<int FIN>
__global__ __launch_bounds__(256) void conv_gemm_k(
        const float* __restrict__ A, const float* __restrict__ W,
        const float* __restrict__ x, const float* __restrict__ root,
        const float* __restrict__ bias, const int* __restrict__ rowptr,
        int n, float* __restrict__ out){
    constexpr int K = 25 * FIN;
    constexpr int MR = 16;
    int wid = threadIdx.x >> 6, lane = threadIdx.x & 63;
    int r0 = (blockIdx.x * 4 + wid) * MR;
    if (r0 >= n) return;

    float cacc[MR];
    #pragma unroll
    for (int m = 0; m < MR; m++) cacc[m] = 0.f;

    int aoff[MR];   // row offsets in float4 units, forced wave-uniform
    #pragma unroll
    for (int m = 0; m < MR; m++){
        int rr = min(r0 + m, n - 1);
        aoff[m] = __builtin_amdgcn_readfirstlane(rr * (K / 4));
    }
    const float4* __restrict__ A4 = (const float4*)A;

    for (int kc = 0; kc < K; kc += 32){
        float wreg[32];
        #pragma unroll
        for (int k = 0; k < 32; k++) wreg[k] = W[(size_t)(kc + k) * 64 + lane];
        #pragma unroll
        for (int m = 0; m < MR; m++){
            #pragma unroll
            for (int k4 = 0; k4 < 8; k4++){
                float4 a = A4[aoff[m] + (kc >> 2) + k4];
                cacc[m] = fmaf(a.x, wreg[k4*4 + 0], cacc[m]);
                cacc[m] = fmaf(a.y, wreg[k4*4 + 1], cacc[m]);
                cacc[m] = fmaf(a.z, wreg[k4*4 + 2], cacc[m]);
                cacc[m] = fmaf(a.w, wreg[k4*4 + 3], cacc[m]);
            }
        }
    }

    float bw = bias[lane];
    #pragma unroll
    for (int m = 0; m < MR; m++){
        int row = r0 + m;
        if (row >= n) break;
        int d0 = rowptr[row], d1 = rowptr[row + 1];
        float degv = (float)max(d1 - d0, 1);
        float rsum = 0.f;
        const float* xr = x + (size_t)row * FIN;
        #pragma unroll
        for (int f = 0; f < FIN; f++) rsum = fmaf(xr[f], root[(size_t)f * 64 + lane], rsum);
        float v = cacc[m] / degv + rsum + bw;
        out[(size_t)row * 64 + lane] = eluf(v);
    }
}

// ---------------- MLP head + log_softmax ----------------
__global__ void mlp_k(const float* __restrict__ px, const float* __restrict__ fw1,
                      const float* __restrict__ fb1, const float* __restrict__ fw2,
                      const float* __restrict__ fb2, float* __restrict__ out){
    __shared__ float xr[256];
    __shared__ float h[128];
    __shared__ float lg[10];
    __shared__ float lse;
    int g = blockIdx.x, t = threadIdx.x;
    xr[t]       = px[(size_t)g*256 + t];
    xr[t + 128] = px[(size_t)g*256 + 128 + t];
    __syncthreads();
    float s = fb1[t];
    const float* wrow = fw1 + (size_t)t * 256;
    #pragma unroll 8
    for (int i = 0; i < 256; i++) s += xr[i] * wrow[i];
    h[t] = eluf(s);
    __syncthreads();
    if (t < 10){
        float s2 = fb2[t];
        const float* w2 = fw2 + (size_t)t * 128;
        for (int j = 0; j < 128; j++) s2 += h[j] * w2[j];
        lg[t] = s2;
    }
    __syncthreads();
    if (t == 0){
        float m = lg[0];
        for (int c = 1; c < 10; c++) m = fmaxf(m, lg[c]);
        float se = 0.f;
        for (int c = 0; c < 10; c++) se += expf(lg[c] - m);
        lse = m + logf(se);
    }
    __syncthreads();
    if (t < 10) out[(size_t)g*10 + t] = lg[t] - lse;
}

extern "C" void kernel_launch(void* const* d_in, const int* in_sizes, int n_in,
                              void* d_out, int out_size, void* d_ws, size_t ws_size,
                              hipStream_t stream) {
    const float* x   = (const float*)d_in[0];
    const float* pos = (const float*)d_in[1];
    const int*   src = (const int*)d_in[2];
    const int*   dst = (const int*)d_in[3];
    const float* W1  = (const float*)d_in[4];
    const float* r1  = (const float*)d_in[5];
    const float* b1  = (const float*)d_in[6];
    const float* W2  = (const float*)d_in[7];
    const float* r2  = (const float*)d_in[8];
    const float* b2  = (const float*)d_in[9];
    const float* W3  = (const float*)d_in[10];
    const float* r3  = (const float*)d_in[11];
    const float* b3  = (const float*)d_in[12];
    const float* fw1 = (const float*)d_in[13];
    const float* fb1 = (const float*)d_in[14];
    const float* fw2 = (const float*)d_in[15];
    const float* fb2 = (const float*)d_in[16];
    float* out = (float*)d_out;

    const int N  = in_sizes[0];
    const int E  = in_sizes[2];
    const int B  = N / NPG;
    const int S1 = B * 36;
    const int S2 = B * 25;
    const int B4 = B * 4;

    float* w = (float*)d_ws;
    size_t off = 0;
    auto alloc = [&](size_t nelem){ size_t o = off; off += (nelem + 63) & ~(size_t)63; return o; };

    // zero-init region
    size_t o_scal = alloc(4);                 // amax0, amax1, amax2 (uint bits of nonneg floats)
    size_t o_acc1 = alloc((size_t)N * 25);
    size_t o_deg1 = alloc(N);
    size_t o_cnt1 = alloc(S1);
    size_t o_pp1  = alloc((size_t)S1 * 2);
    size_t o_px1  = alloc((size_t)S1 * 32);
    size_t o_deg2 = alloc(S1);
    size_t o_cnt2 = alloc(S2);
    size_t o_pp2  = alloc((size_t)S2 * 2);
    size_t o_px2  = alloc((size_t)S2 * 64);
    size_t o_deg3 = alloc(S2);
    size_t o_cnt3 = alloc(B4);
    size_t o_pp3  = alloc((size_t)B4 * 2);
    size_t o_px3  = alloc((size_t)B4 * 64);
    size_t zeroEnd = off;
    // 0xFF-init region (pair markers, atomicMin with UINT_MAX init)
    size_t o_pm1 = alloc((size_t)B * 36 * 36);
    size_t o_pm2 = alloc((size_t)B * 25 * 25);
    size_t ffEnd = off;
    // no-init region (fully written before read)
    size_t o_out1  = alloc((size_t)N * 32);
    size_t o_out2  = alloc((size_t)S1 * 64);
    size_t o_out3  = alloc((size_t)S2 * 64);
    size_t o_cl1   = alloc(N);
    size_t o_sv1   = alloc(S1);
    size_t o_es1   = alloc(E);
    size_t o_ed1   = alloc(E);
    size_t o_kf1   = alloc((E + 3) / 4);
    size_t o_cl2   = alloc(S1);
    size_t o_sv2   = alloc(S2);
    size_t o_es2   = alloc(E);
    size_t o_ed2   = alloc(E);
    size_t o_kf2   = alloc((E + 3) / 4);
    size_t o_cl3   = alloc(S2);
    size_t o_sv3   = alloc(B4);
    size_t o_rp2   = alloc(S1 + 1);
    size_t o_cur2  = alloc(S1);
    size_t o_el2   = alloc(E);
    size_t o_rp3   = alloc(S2 + 1);
    size_t o_cur3  = alloc(S2);
    size_t o_el3   = alloc(E);
    // big A scratch (union: conv2 uses S1*800, conv3 uses S2*1600; sequential)
    size_t accAelems = (size_t)S1 * 800 > (size_t)S2 * 1600 ? (size_t)S1 * 800 : (size_t)S2 * 1600;
    size_t o_accA  = alloc(accAelems);

    hipMemsetAsync(w, 0, zeroEnd * sizeof(float), stream);
    hipMemsetAsync((char*)d_ws + zeroEnd * sizeof(float), 0xFF, (ffEnd - zeroEnd) * sizeof(float), stream);

    unsigned* scal = (unsigned*)(w + o_scal);
    auto nb = [](long long t){ return (unsigned)((t + 255) / 256); };
    auto nb4 = [](long long t){ return (unsigned)((t + 3) / 4); };

    // stage 1: conv1 on original graph
    amax0_k<<<nb(E), 256, 0, stream>>>(pos, src, dst, E, scal + 0);
    conv1_edge_k<<<nb(E), 256, 0, stream>>>(x, pos, src, dst, E, scal + 0, w + o_acc1, w + o_deg1);
    conv1_node_k<<<nb((long long)N * 32), 256, 0, stream>>>(w + o_acc1, w + o_deg1, x, W1, r1, b1, N, w + o_out1);

    // pool 1 (size=5, G=6)
    pool_node_k<5><<<nb((long long)N * 32), 256, 0, stream>>>(
        w + o_out1, pos, nullptr, N, 5.f, 6, NPG,
        (int*)(w + o_cl1), (unsigned*)(w + o_px1), w + o_cnt1, w + o_pp1);
    pool_fin_k<5><<<nb((long long)S1 * 32), 256, 0, stream>>>(
        (unsigned*)(w + o_px1), w + o_cnt1, w + o_pp1, w + o_sv1, S1);
    dedup_a_k<<<nb(E), 256, 0, stream>>>(src, dst, (int*)(w + o_cl1), nullptr, E, 36,
                                         (int*)(w + o_es1), (int*)(w + o_ed1), (unsigned*)(w + o_pm1));
    dedup_b_k<<<nb(E), 256, 0, stream>>>((int*)(w + o_es1), (int*)(w + o_ed1), nullptr,
                                         (unsigned*)(w + o_pm1), w + o_pp1, E, 36,
                                         (unsigned char*)(w + o_kf1), w + o_deg2, scal + 1);

    // conv2 (Fin=32 -> 64) on S1 clusters: CSR + gather-to-global + GEMM
    scan_k<<<1, 1024, 0, stream>>>(w + o_deg2, S1, (int*)(w + o_rp2), (int*)(w + o_cur2));
    csr_fill_k<<<nb(E), 256, 0, stream>>>((unsigned char*)(w + o_kf1), (int*)(w + o_ed1), E,
                                          (int*)(w + o_cur2), (int*)(w + o_el2));
    conv_gather_k<32><<<nb4(S1), 256, 0, stream>>>(
        w + o_px1, w + o_pp1, (int*)(w + o_es1), (int*)(w + o_el2), (int*)(w + o_rp2),
        scal + 1, S1, w + o_accA);
    conv_gemm_k<32><<<nb((long long)S1 * 4), 256, 0, stream>>>(
        w + o_accA, W2, w + o_px1, r2, b2, (int*)(w + o_rp2), S1, w + o_out2);

    // pool 2 (size=7, G=5)
    pool_node_k<6><<<nb((long long)S1 * 64), 256, 0, stream>>>(
        w + o_out2, w + o_pp1, w + o_sv1, S1, 7.f, 5, 36,
        (int*)(w + o_cl2), (unsigned*)(w + o_px2), w + o_cnt2, w + o_pp2);
    pool_fin_k<6><<<nb((long long)S2 * 64), 256, 0, stream>>>(
        (unsigned*)(w + o_px2), w + o_cnt2, w + o_pp2, w + o_sv2, S2);
    dedup_a_k<<<nb(E), 256, 0, stream>>>((int*)(w + o_es1), (int*)(w + o_ed1), (int*)(w + o_cl2),
                                         (unsigned char*)(w + o_kf1), E, 25,
                                         (int*)(w + o_es2), (int*)(w + o_ed2), (unsigned*)(w + o_pm2));
    dedup_b_k<<<nb(E), 256, 0, stream>>>((int*)(w + o_es2), (int*)(w + o_ed2),
                                         (unsigned char*)(w + o_kf1), (unsigned*)(w + o_pm2),
                                         w + o_pp2, E, 25,
                                         (unsigned char*)(w + o_kf2), w + o_deg3, scal + 2);

    // conv3 (Fin=64 -> 64) on S2 clusters: CSR + gather-to-global + GEMM
    scan_k<<<1, 1024, 0, stream>>>(w + o_deg3, S2, (int*)(w + o_rp3), (int*)(w + o_cur3));
    csr_fill_k<<<nb(E), 256, 0, stream>>>((unsigned char*)(w + o_kf2), (int*)(w + o_ed2), E,
                                          (int*)(w + o_cur3), (int*)(w + o_el3));
    conv_gather_k<64><<<nb4(S2), 256, 0, stream>>>(
        w + o_px2, w + o_pp2, (int*)(w + o_es2), (int*)(w + o_el3), (int*)(w + o_rp3),
        scal + 2, S2, w + o_accA);
    conv_gemm_k<64><<<nb((long long)S2 * 4), 256, 0, stream>>>(
        w + o_accA, W3, w + o_px2, r3, b3, (int*)(w + o_rp3), S2, w + o_out3);

    // final max_pool_x (size=14, G=2) — reuse generic pooling; pos/cl/sval outputs unused
    pool_node_k<6><<<nb((long long)S2 * 64), 256, 0, stream>>>(
        w + o_out3, w + o_pp2, w + o_sv2, S2, 14.f, 2, 25,
        (int*)(w + o_cl3), (unsigned*)(w + o_px3), w + o_cnt3, w + o_pp3);
    pool_fin_k<6><<<nb((long long)B4 * 64), 256, 0, stream>>>(
        (unsigned*)(w + o_px3), w + o_cnt3, w + o_pp3, w + o_sv3, B4);

    // MLP head + log_softmax
    mlp_k<<<B, 128, 0, stream>>>(w + o_px3, fw1, fb1, fw2, fb2, out);
}

// Round 5
// 1191.593 us; speedup vs baseline: 1.5937x; 1.5937x over previous
//
#include <hip/hip_runtime.h>
#include <math.h>

#define NPG 75
#define KDIM 5

__device__ __forceinline__ float eluf(float v){ return v > 0.f ? v : expf(v) - 1.f; }

// order-preserving float <-> uint encoding (for atomicMax-based segment max)
__device__ __forceinline__ unsigned fenc(float f){
    unsigned u = __float_as_uint(f);
    return (u & 0x80000000u) ? ~u : (u | 0x80000000u);
}
__device__ __forceinline__ float fdec(unsigned u){
    return (u & 0x80000000u) ? __uint_as_float(u & 0x7FFFFFFFu) : __uint_as_float(~u);
}

// spline basis: pseudo = cart/(2*amax)+0.5, clip[0,1], *4; 4 corner weights + kernel ids
__device__ __forceinline__ void spline2(float c0, float c1, float am, int* kks, float* wsp){
    float denom = 2.f * fmaxf(am, 1e-12f);
    float p0 = c0 / denom + 0.5f;
    float p1 = c1 / denom + 0.5f;
    p0 = fminf(fmaxf(p0, 0.f), 1.f) * 4.f;
    p1 = fminf(fmaxf(p1, 0.f), 1.f) * 4.f;
    float b0 = fminf(floorf(p0), 3.f);
    float b1 = fminf(floorf(p1), 3.f);
    float f0 = p0 - b0, f1 = p1 - b1;
    int i0 = (int)b0, i1 = (int)b1;
    wsp[0] = (1.f - f0) * (1.f - f1); kks[0] = i0     + KDIM *  i1;
    wsp[1] =        f0  * (1.f - f1); kks[1] = i0 + 1 + KDIM *  i1;
    wsp[2] = (1.f - f0) *        f1 ; kks[2] = i0     + KDIM * (i1 + 1);
    wsp[3] =        f0  *        f1 ; kks[3] = i0 + 1 + KDIM * (i1 + 1);
}

// ---------------- amax over |pos[src]-pos[dst]| (all edges) ----------------
__global__ void amax0_k(const float* __restrict__ pos, const int* __restrict__ src,
                        const int* __restrict__ dst, int E, unsigned* __restrict__ amax){
    int e = blockIdx.x * 256 + threadIdx.x;
    float cand = 0.f;
    if (e < E){
        int s = src[e], d = dst[e];
        float c0 = pos[s*2]   - pos[d*2];
        float c1 = pos[s*2+1] - pos[d*2+1];
        cand = fmaxf(fabsf(c0), fabsf(c1));
    }
    __shared__ float sm[256];
    sm[threadIdx.x] = cand; __syncthreads();
    for (int o = 128; o > 0; o >>= 1){
        if (threadIdx.x < o) sm[threadIdx.x] = fmaxf(sm[threadIdx.x], sm[threadIdx.x + o]);
        __syncthreads();
    }
    if (threadIdx.x == 0 && sm[0] > 0.f) atomicMax(amax, __float_as_uint(sm[0]));
}

// ---------------- conv1: aggregate (Fin=1) ----------------
__global__ void conv1_edge_k(const float* __restrict__ x, const float* __restrict__ pos,
                             const int* __restrict__ src, const int* __restrict__ dst, int E,
                             const unsigned* __restrict__ amaxp,
                             float* __restrict__ acc, float* __restrict__ deg){
    int e = blockIdx.x * 256 + threadIdx.x;
    if (e >= E) return;
    int s = src[e], d = dst[e];
    float am = __uint_as_float(*amaxp);
    float c0 = pos[s*2]   - pos[d*2];
    float c1 = pos[s*2+1] - pos[d*2+1];
    int kks[4]; float wsp[4];
    spline2(c0, c1, am, kks, wsp);
    float xv = x[s];
    #pragma unroll
    for (int c = 0; c < 4; c++) atomicAdd(&acc[(size_t)d*25 + kks[c]], wsp[c] * xv);
    atomicAdd(&deg[d], 1.f);
}

__global__ void conv1_node_k(const float* __restrict__ acc, const float* __restrict__ deg,
                             const float* __restrict__ x, const float* __restrict__ W1,
                             const float* __restrict__ r1, const float* __restrict__ b1,
                             int N, float* __restrict__ out){
    int gid = blockIdx.x * 256 + threadIdx.x;
    int i = gid >> 5, o = gid & 31;
    if (i >= N) return;
    float sum = 0.f;
    #pragma unroll
    for (int k = 0; k < 25; k++) sum += acc[(size_t)i*25 + k] * W1[k*32 + o];
    float v = sum / fmaxf(deg[i], 1.f) + x[i] * r1[o] + b1[o];
    out[(size_t)i*32 + o] = eluf(v);
}

// ---------------- generic pooling ----------------
template<int LOGF>
__global__ void pool_node_k(const float* __restrict__ x, const float* __restrict__ pos,
                            const float* __restrict__ valid, int n, float size, int G, int npg,
                            int* __restrict__ cl, unsigned* __restrict__ pxenc,
                            float* __restrict__ cnt, float* __restrict__ possum){
    const int F = 1 << LOGF;
    int gid = blockIdx.x * 256 + threadIdx.x;
    int i = gid >> LOGF, f = gid & (F - 1);
    if (i >= n) return;
    float p0 = pos[i*2], p1 = pos[i*2+1];
    int c0 = min(max((int)floorf(p0 / size), 0), G - 1);
    int c1 = min(max((int)floorf(p1 / size), 0), G - 1);
    int b = i / npg;
    int c = b * G * G + c1 * G + c0;
    if (f == 0) cl[i] = c;
    float vld = valid ? valid[i] : 1.f;
    if (vld > 0.f){
        atomicMax(&pxenc[(size_t)c*F + f], fenc(x[(size_t)i*F + f]));
        if (f == 0){
            atomicAdd(&cnt[c], 1.f);
            atomicAdd(&possum[c*2],     p0);
            atomicAdd(&possum[c*2 + 1], p1);
        }
    }
}

template<int LOGF>
__global__ void pool_fin_k(unsigned* __restrict__ pxenc, const float* __restrict__ cnt,
                           float* __restrict__ possum, float* __restrict__ sval, int S){
    const int F = 1 << LOGF;
    int gid = blockIdx.x * 256 + threadIdx.x;
    int s = gid >> LOGF, f = gid & (F - 1);
    if (s >= S) return;
    float c = cnt[s];
    float v = (c > 0.f) ? fdec(pxenc[(size_t)s*F + f]) : 0.f;
    ((float*)pxenc)[(size_t)s*F + f] = v;
    if (f == 0){
        float m = fmaxf(c, 1.f);
        possum[s*2]     /= m;
        possum[s*2 + 1] /= m;
        sval[s] = (c > 0.f) ? 1.f : 0.f;
    }
}

// ---------------- edge remap + dedup ----------------
// NOTE: no __restrict__ on in/out edge arrays — stage 2 remaps IN-PLACE.
__global__ void dedup_a_k(const int* esrc_in, const int* edst_in,
                          const int* __restrict__ clmap, const unsigned char* __restrict__ maskin,
                          int E, int GG, int* esrc_out, int* edst_out,
                          unsigned* __restrict__ pairmark){
    int e = blockIdx.x * 256 + threadIdx.x;
    if (e >= E) return;
    int a = clmap[esrc_in[e]], b = clmap[edst_in[e]];
    esrc_out[e] = a; edst_out[e] = b;
    bool m = (maskin ? (maskin[e] != 0) : true) && (a != b);
    if (m){
        int g = a / GG;
        unsigned key = (unsigned)((size_t)g * GG * GG + (a - g * GG) * GG + (b - g * GG));
        atomicMin(&pairmark[key], (unsigned)e);
    }
}

__global__ void dedup_b_k(const int* __restrict__ esrc, const int* __restrict__ edst,
                          const unsigned char* __restrict__ maskin, const unsigned* __restrict__ pairmark,
                          const float* __restrict__ ppos, int E, int GG,
                          unsigned char* __restrict__ kf, float* __restrict__ deg,
                          unsigned* __restrict__ amax){
    int e = blockIdx.x * 256 + threadIdx.x;
    float cand = 0.f;
    if (e < E){
        int a = esrc[e], b = edst[e];
        bool m = (maskin ? (maskin[e] != 0) : true) && (a != b);
        bool kept = false;
        if (m){
            int g = a / GG;
            unsigned key = (unsigned)((size_t)g * GG * GG + (a - g * GG) * GG + (b - g * GG));
            kept = (pairmark[key] == (unsigned)e);
        }
        kf[e] = kept ? 1 : 0;
        if (kept){
            float c0 = ppos[a*2]   - ppos[b*2];
            float c1 = ppos[a*2+1] - ppos[b*2+1];
            cand = fmaxf(fabsf(c0), fabsf(c1));
            atomicAdd(&deg[b], 1.f);
        }
    }
    __shared__ float sm[256];
    sm[threadIdx.x] = cand; __syncthreads();
    for (int o = 128; o > 0; o >>= 1){
        if (threadIdx.x < o) sm[threadIdx.x] = fmaxf(sm[threadIdx.x], sm[threadIdx.x + o]);
        __syncthreads();
    }
    if (threadIdx.x == 0 && sm[0] > 0.f) atomicMax(amax, __float_as_uint(sm[0]));
}

// ---------------- CSR build: exclusive scan of deg + fill ----------------
__global__ void scan_k(const float* __restrict__ deg, int n,
                       int* __restrict__ rowptr, int* __restrict__ cursor){
    __shared__ int wt[16];
    __shared__ int wo[17];
    __shared__ int carry;
    int t = threadIdx.x, lane = t & 63, wid = t >> 6;
    if (t == 0) carry = 0;
    __syncthreads();
    for (int base = 0; base < n; base += 1024){
        int i = base + t;
        int v = (i < n) ? (int)deg[i] : 0;
        int incl = v;
        #pragma unroll
        for (int o = 1; o < 64; o <<= 1){
            int u = __shfl_up(incl, o, 64);
            if (lane >= o) incl += u;
        }
        if (lane == 63) wt[wid] = incl;
        __syncthreads();
        if (t == 0){
            int run = 0;
            #pragma unroll
            for (int wv = 0; wv < 16; wv++){ wo[wv] = run; run += wt[wv]; }
            wo[16] = run;
        }
        __syncthreads();
        int ex = incl - v + wo[wid] + carry;
        if (i < n){ rowptr[i] = ex; cursor[i] = ex; }
        __syncthreads();
        if (t == 0) carry += wo[16];
        __syncthreads();
    }
    if (t == 0) rowptr[n] = carry;
}

__global__ void csr_fill_k(const unsigned char* __restrict__ kf, const int* __restrict__ edst,
                           int E, int* __restrict__ cursor, int* __restrict__ elist){
    int e = blockIdx.x * 256 + threadIdx.x;
    if (e >= E) return;
    if (!kf[e]) return;
    int idx = atomicAdd(&cursor[edst[e]], 1);
    elist[idx] = e;
}

// ---------------- W' = [W ; root] concat (K' = 26*FIN rows x 64 cols) ----------------
__global__ void wconcat_k(const float* __restrict__ W, const float* __restrict__ root,
                          int FIN, float* __restrict__ Wc){
    int i = blockIdx.x * 256 + threadIdx.x;
    int tot = 26 * FIN * 64;
    if (i >= tot) return;
    int k = i >> 6, c = i & 63;
    Wc[i] = (k < 25 * FIN) ? W[i] : root[(size_t)(k - 25 * FIN) * 64 + c];
}

// ---------------- conv2/conv3 phase A: CSR gather into LDS, dump A' rows ----------------
// A'[node] = [acc/deg (25*FIN) | x[node] (FIN)], stride 26*FIN.
template<int FIN>
__global__ __launch_bounds__(256) void conv_gather_k(
        const float* __restrict__ x, const float* __restrict__ ppos,
        const int* __restrict__ esrc, const int* __restrict__ elist,
        const int* __restrict__ rowptr, const unsigned* __restrict__ amaxp,
        int n, float* __restrict__ Aout){
    constexpr int EPB = (FIN == 32) ? 2 : 1;
    constexpr int ACC = 25 * FIN;
    constexpr int KTOT = 26 * FIN;
    __shared__ float acc[4 * EPB * ACC];           // 25.6 KB
    int g = threadIdx.x >> 6, lane = threadIdx.x & 63;
    int node = blockIdx.x * 4 + g;
    float* accg = acc + g * EPB * ACC;

    for (int i = threadIdx.x; i < 4 * EPB * ACC; i += 256) acc[i] = 0.f;
    __syncthreads();

    int row0 = 0, row1 = 0;
    if (node < n){
        row0 = rowptr[node]; row1 = rowptr[node + 1];
        float am = __uint_as_float(*amaxp);
        float pd0 = ppos[node*2], pd1 = ppos[node*2 + 1];
        int ebuf = (EPB == 2) ? (lane >> 5) : 0;
        int f = lane & (FIN - 1);
        float* ab = accg + ebuf * ACC;
        for (int i = row0 + ebuf; i < row1; i += EPB){
            int e = elist[i];
            int a = esrc[e];
            float c0 = ppos[a*2]     - pd0;
            float c1 = ppos[a*2 + 1] - pd1;
            int kks[4]; float wsp[4];
            spline2(c0, c1, am, kks, wsp);
            float xv = x[(size_t)a * FIN + f];
            #pragma unroll
            for (int c = 0; c < 4; c++) ab[kks[c] * FIN + f] += wsp[c] * xv;
        }
    }
    __syncthreads();

    if (node >= n) return;
    float inv = 1.f / (float)max(row1 - row0, 1);
    float4* dst4 = (float4*)(Aout + (size_t)node * KTOT);
    const float4* s4  = (const float4*)accg;
    const float4* s4b = (const float4*)(accg + ACC);
    #pragma unroll 2
    for (int j = lane; j < ACC / 4; j += 64){
        float4 v = s4[j];
        if (EPB == 2){
            float4 u = s4b[j];
            v.x += u.x; v.y += u.y; v.z += u.z; v.w += u.w;
        }
        v.x *= inv; v.y *= inv; v.z *= inv; v.w *= inv;
        dst4[j] = v;
    }
    const float4* x4 = (const float4*)(x + (size_t)node * FIN);
    for (int j = lane; j < FIN / 4; j += 64) dst4[ACC / 4 + j] = x4[j];
}

// ---------------- conv2/conv3 phase B: tiled SGEMM + fused bias/ELU ----------------
// out[M][64] = elu( A'[M][K'] x Wc[K'][64] + bias ). Tile 64x64, 256 threads,
// thread tile 4x4, K-step 32 (prefetch before first sync overlaps compute).
template<int FIN>
__global__ __launch_bounds__(256) void conv_sgemm_k(
        const float* __restrict__ A, const float* __restrict__ Wc,
        const float* __restrict__ bias, int M, float* __restrict__ out){
    constexpr int KTOT = 26 * FIN;
    __shared__ float As[32][64];   // [k][row]
    __shared__ float Ws[32][64];   // [k][col]
    const int t = threadIdx.x;
    const int m0 = blockIdx.x * 64;

    const int r0 = (t & 15) * 4;
    const int c0 = (t >> 4) * 4;

    float accr[4][4];
    #pragma unroll
    for (int i = 0; i < 4; i++)
        #pragma unroll
        for (int j = 0; j < 4; j++) accr[i][j] = 0.f;

    for (int ks = 0; ks < KTOT; ks += 32){
        float4 av[2], wv[2];
        #pragma unroll
        for (int i = 0; i < 2; i++){
            int idx = t + i * 256;            // 0..511
            int arow = idx >> 3, ak4 = idx & 7;
            av[i] = *(const float4*)&A[(size_t)(m0 + arow) * KTOT + ks + ak4 * 4];
            int wk = idx >> 4, wc4 = idx & 15;
            wv[i] = *(const float4*)&Wc[(size_t)(ks + wk) * 64 + wc4 * 4];
        }
        __syncthreads();
        #pragma unroll
        for (int i = 0; i < 2; i++){
            int idx = t + i * 256;
            int arow = idx >> 3, ak4 = idx & 7;
            As[ak4*4 + 0][arow] = av[i].x;
            As[ak4*4 + 1][arow] = av[i].y;
            As[ak4*4 + 2][arow] = av[i].z;
            As[ak4*4 + 3][arow] = av[i].w;
            int wk = idx >> 4, wc4 = idx & 15;
            *(float4*)&Ws[wk][wc4 * 4] = wv[i];
        }
        __syncthreads();
        #pragma unroll
        for (int k = 0; k < 32; k++){
            float4 a = *(const float4*)&As[k][r0];
            float4 b = *(const float4*)&Ws[k][c0];
            accr[0][0] = fmaf(a.x, b.x, accr[0][0]);
            accr[0][1] = fmaf(a.x, b.y, accr[0][1]);
            accr[0][2] = fmaf(a.x, b.z, accr[0][2]);
            accr[0][3] = fmaf(a.x, b.w, accr[0][3]);
            accr[1][0] = fmaf(a.y, b.x, accr[1][0]);
            accr[1][1] = fmaf(a.y, b.y, accr[1][1]);
            accr[1][2] = fmaf(a.y, b.z, accr[1][2]);
            accr[1][3] = fmaf(a.y, b.w, accr[1][3]);
            accr[2][0] = fmaf(a.z, b.x, accr[2][0]);
            accr[2][1] = fmaf(a.z, b.y, accr[2][1]);
            accr[2][2] = fmaf(a.z, b.z, accr[2][2]);
            accr[2][3] = fmaf(a.z, b.w, accr[2][3]);
            accr[3][0] = fmaf(a.w, b.x, accr[3][0]);
            accr[3][1] = fmaf(a.w, b.y, accr[3][1]);
            accr[3][2] = fmaf(a.w, b.z, accr[3][2]);
            accr[3][3] = fmaf(a.w, b.w, accr[3][3]);
        }
    }

    const float4 bi = *(const float4*)&bias[c0];
    #pragma unroll
    for (int i = 0; i < 4; i++){
        float4 v;
        v.x = eluf(accr[i][0] + bi.x);
        v.y = eluf(accr[i][1] + bi.y);
        v.z = eluf(accr[i][2] + bi.z);
        v.w = eluf(accr[i][3] + bi.w);
        *(float4*)&out[(size_t)(m0 + r0 + i) * 64 + c0] = v;
    }
}

// ---------------- MLP head + log_softmax ----------------
__global__ void mlp_k(const float* __restrict__ px, const float* __restrict__ fw1,
                      const float* __restrict__ fb1, const float* __restrict__ fw2,
                      const float* __restrict__ fb2, float* __restrict__ out){
    __shared__ float xr[256];
    __shared__ float h[128];
    __shared__ float lg[10];
    __shared__ float lse;
    int g = blockIdx.x, t = threadIdx.x;
    xr[t]       = px[(size_t)g*256 + t];
    xr[t + 128] = px[(size_t)g*256 + 128 + t];
    __syncthreads();
    float s = fb1[t];
    const float* wrow = fw1 + (size_t)t * 256;
    #pragma unroll 8
    for (int i = 0; i < 256; i++) s += xr[i] * wrow[i];
    h[t] = eluf(s);
    __syncthreads();
    if (t < 10){
        float s2 = fb2[t];
        const float* w2 = fw2 + (size_t)t * 128;
        for (int j = 0; j < 128; j++) s2 += h[j] * w2[j];
        lg[t] = s2;
    }
    __syncthreads();
    if (t == 0){
        float m = lg[0];
        for (int c = 1; c < 10; c++) m = fmaxf(m, lg[c]);
        float se = 0.f;
        for (int c = 0; c < 10; c++) se += expf(lg[c] - m);
        lse = m + logf(se);
    }
    __syncthreads();
    if (t < 10) out[(size_t)g*10 + t] = lg[t] - lse;
}

extern "C" void kernel_launch(void* const* d_in, const int* in_sizes, int n_in,
                              void* d_out, int out_size, void* d_ws, size_t ws_size,
                              hipStream_t stream) {
    const float* x   = (const float*)d_in[0];
    const float* pos = (const float*)d_in[1];
    const int*   src = (const int*)d_in[2];
    const int*   dst = (const int*)d_in[3];
    const float* W1  = (const float*)d_in[4];
    const float* r1  = (const float*)d_in[5];
    const float* b1  = (const float*)d_in[6];
    const float* W2  = (const float*)d_in[7];
    const float* r2  = (const float*)d_in[8];
    const float* b2  = (const float*)d_in[9];
    const float* W3  = (const float*)d_in[10];
    const float* r3  = (const float*)d_in[11];
    const float* b3  = (const float*)d_in[12];
    const float* fw1 = (const float*)d_in[13];
    const float* fb1 = (const float*)d_in[14];
    const float* fw2 = (const float*)d_in[15];
    const float* fb2 = (const float*)d_in[16];
    float* out = (float*)d_out;

    const int N  = in_sizes[0];
    const int E  = in_sizes[2];
    const int B  = N / NPG;
    const int S1 = B * 36;
    const int S2 = B * 25;
    const int B4 = B * 4;

    float* w = (float*)d_ws;
    size_t off = 0;
    auto alloc = [&](size_t nelem){ size_t o = off; off += (nelem + 63) & ~(size_t)63; return o; };

    // zero-init region
    size_t o_scal = alloc(4);                 // amax0, amax1, amax2 (uint bits of nonneg floats)
    size_t o_acc1 = alloc((size_t)N * 25);
    size_t o_deg1 = alloc(N);
    size_t o_cnt1 = alloc(S1);
    size_t o_pp1  = alloc((size_t)S1 * 2);
    size_t o_px1  = alloc((size_t)S1 * 32);
    size_t o_deg2 = alloc(S1);
    size_t o_cnt2 = alloc(S2);
    size_t o_pp2  = alloc((size_t)S2 * 2);
    size_t o_px2  = alloc((size_t)S2 * 64);
    size_t o_deg3 = alloc(S2);
    size_t o_cnt3 = alloc(B4);
    size_t o_pp3  = alloc((size_t)B4 * 2);
    size_t o_px3  = alloc((size_t)B4 * 64);
    size_t zeroEnd = off;
    // 0xFF-init region (pair markers, atomicMin with UINT_MAX init)
    size_t o_pm1 = alloc((size_t)B * 36 * 36);
    size_t o_pm2 = alloc((size_t)B * 25 * 25);
    size_t ffEnd = off;
    // no-init region (fully written before read)
    size_t o_out1  = alloc((size_t)N * 32);
    size_t o_out2  = alloc((size_t)S1 * 64);
    size_t o_out3  = alloc((size_t)S2 * 64);
    size_t o_cl1   = alloc(N);
    size_t o_sv1   = alloc(S1);
    size_t o_es1   = alloc(E);            // stage-2 remap happens IN-PLACE here
    size_t o_ed1   = alloc(E);
    size_t o_kf1   = alloc((E + 3) / 4);
    size_t o_cl2   = alloc(S1);
    size_t o_sv2   = alloc(S2);
    size_t o_kf2   = alloc((E + 3) / 4);
    size_t o_cl3   = alloc(S2);
    size_t o_sv3   = alloc(B4);
    size_t o_rp2   = alloc(S1 + 1);
    size_t o_cur2  = alloc(S1);
    size_t o_el2   = alloc(E);            // reused as el3 (dead after conv2 gather)
    size_t o_rp3   = alloc(S2 + 1);
    size_t o_cur3  = alloc(S2);
    size_t o_wc    = alloc((size_t)26 * 64 * 64);                 // W' concat (max 1664x64)
    // big A' scratch (union: conv2 S1*832, conv3 S2*1664; sequential use)
    size_t accAelems = (size_t)S1 * 832 > (size_t)S2 * 1664 ? (size_t)S1 * 832 : (size_t)S2 * 1664;
    size_t o_accA  = alloc(accAelems);

    hipMemsetAsync(w, 0, zeroEnd * sizeof(float), stream);
    hipMemsetAsync((char*)d_ws + zeroEnd * sizeof(float), 0xFF, (ffEnd - zeroEnd) * sizeof(float), stream);

    unsigned* scal = (unsigned*)(w + o_scal);
    auto nb = [](long long t){ return (unsigned)((t + 255) / 256); };
    auto nb4 = [](long long t){ return (unsigned)((t + 3) / 4); };

    // stage 1: conv1 on original graph
    amax0_k<<<nb(E), 256, 0, stream>>>(pos, src, dst, E, scal + 0);
    conv1_edge_k<<<nb(E), 256, 0, stream>>>(x, pos, src, dst, E, scal + 0, w + o_acc1, w + o_deg1);
    conv1_node_k<<<nb((long long)N * 32), 256, 0, stream>>>(w + o_acc1, w + o_deg1, x, W1, r1, b1, N, w + o_out1);

    // pool 1 (size=5, G=6)
    pool_node_k<5><<<nb((long long)N * 32), 256, 0, stream>>>(
        w + o_out1, pos, nullptr, N, 5.f, 6, NPG,
        (int*)(w + o_cl1), (unsigned*)(w + o_px1), w + o_cnt1, w + o_pp1);
    pool_fin_k<5><<<nb((long long)S1 * 32), 256, 0, stream>>>(
        (unsigned*)(w + o_px1), w + o_cnt1, w + o_pp1, w + o_sv1, S1);
    dedup_a_k<<<nb(E), 256, 0, stream>>>(src, dst, (int*)(w + o_cl1), nullptr, E, 36,
                                         (int*)(w + o_es1), (int*)(w + o_ed1), (unsigned*)(w + o_pm1));
    dedup_b_k<<<nb(E), 256, 0, stream>>>((int*)(w + o_es1), (int*)(w + o_ed1), nullptr,
                                         (unsigned*)(w + o_pm1), w + o_pp1, E, 36,
                                         (unsigned char*)(w + o_kf1), w + o_deg2, scal + 1);

    // conv2 (Fin=32 -> 64) on S1 clusters
    scan_k<<<1, 1024, 0, stream>>>(w + o_deg2, S1, (int*)(w + o_rp2), (int*)(w + o_cur2));
    csr_fill_k<<<nb(E), 256, 0, stream>>>((unsigned char*)(w + o_kf1), (int*)(w + o_ed1), E,
                                          (int*)(w + o_cur2), (int*)(w + o_el2));
    wconcat_k<<<nb(26 * 32 * 64), 256, 0, stream>>>(W2, r2, 32, w + o_wc);
    conv_gather_k<32><<<nb4(S1), 256, 0, stream>>>(
        w + o_px1, w + o_pp1, (int*)(w + o_es1), (int*)(w + o_el2), (int*)(w + o_rp2),
        scal + 1, S1, w + o_accA);
    conv_sgemm_k<32><<<S1 / 64, 256, 0, stream>>>(w + o_accA, w + o_wc, b2, S1, w + o_out2);

    // pool 2 (size=7, G=5)
    pool_node_k<6><<<nb((long long)S1 * 64), 256, 0, stream>>>(
        w + o_out2, w + o_pp1, w + o_sv1, S1, 7.f, 5, 36,
        (int*)(w + o_cl2), (unsigned*)(w + o_px2), w + o_cnt2, w + o_pp2);
    pool_fin_k<6><<<nb((long long)S2 * 64), 256, 0, stream>>>(
        (unsigned*)(w + o_px2), w + o_cnt2, w + o_pp2, w + o_sv2, S2);
    // in-place remap of es1/ed1 to stage-2 cluster ids
    dedup_a_k<<<nb(E), 256, 0, stream>>>((int*)(w + o_es1), (int*)(w + o_ed1), (int*)(w + o_cl2),
                                         (unsigned char*)(w + o_kf1), E, 25,
                                         (int*)(w + o_es1), (int*)(w + o_ed1), (unsigned*)(w + o_pm2));
    dedup_b_k<<<nb(E), 256, 0, stream>>>((int*)(w + o_es1), (int*)(w + o_ed1),
                                         (unsigned char*)(w + o_kf1), (unsigned*)(w + o_pm2),
                                         w + o_pp2, E, 25,
                                         (unsigned char*)(w + o_kf2), w + o_deg3, scal + 2);

    // conv3 (Fin=64 -> 64) on S2 clusters
    scan_k<<<1, 1024, 0, stream>>>(w + o_deg3, S2, (int*)(w + o_rp3), (int*)(w + o_cur3));
    csr_fill_k<<<nb(E), 256, 0, stream>>>((unsigned char*)(w + o_kf2), (int*)(w + o_ed1), E,
                                          (int*)(w + o_cur3), (int*)(w + o_el2));
    wconcat_k<<<nb(26 * 64 * 64), 256, 0, stream>>>(W3, r3, 64, w + o_wc);
    conv_gather_k<64><<<nb4(S2), 256, 0, stream>>>(
        w + o_px2, w + o_pp2, (int*)(w + o_es1), (int*)(w + o_el2), (int*)(w + o_rp3),
        scal + 2, S2, w + o_accA);
    conv_sgemm_k<64><<<S2 / 64, 256, 0, stream>>>(w + o_accA, w + o_wc, b3, S2, w + o_out3);

    // final max_pool_x (size=14, G=2) — reuse generic pooling; pos/cl/sval outputs unused
    pool_node_k<6><<<nb((long long)S2 * 64), 256, 0, stream>>>(
        w + o_out3, w + o_pp2, w + o_sv2, S2, 14.f, 2, 25,
        (int*)(w + o_cl3), (unsigned*)(w + o_px3), w + o_cnt3, w + o_pp3);
    pool_fin_k<6><<<nb((long long)B4 * 64), 256, 0, stream>>>(
        (unsigned*)(w + o_px3), w + o_cnt3, w + o_pp3, w + o_sv3, B4);

    // MLP head + log_softmax
    mlp_k<<<B, 128, 0, stream>>>(w + o_px3, fw1, fb1, fw2, fb2, out);
}

// Round 6
// 730.104 us; speedup vs baseline: 2.6011x; 1.6321x over previous
//
#include <hip/hip_runtime.h>
#include <math.h>

#define NPG 75
#define KDIM 5

__device__ __forceinline__ float eluf(float v){ return v > 0.f ? v : expf(v) - 1.f; }

// order-preserving float <-> uint encoding (for atomicMax-based segment max)
__device__ __forceinline__ unsigned fenc(float f){
    unsigned u = __float_as_uint(f);
    return (u & 0x80000000u) ? ~u : (u | 0x80000000u);
}
__device__ __forceinline__ float fdec(unsigned u){
    return (u & 0x80000000u) ? __uint_as_float(u & 0x7FFFFFFFu) : __uint_as_float(~u);
}

// spline basis: pseudo = cart/(2*amax)+0.5, clip[0,1], *4; 4 corner weights + kernel ids
__device__ __forceinline__ void spline2(float c0, float c1, float am, int* kks, float* wsp){
    float denom = 2.f * fmaxf(am, 1e-12f);
    float p0 = c0 / denom + 0.5f;
    float p1 = c1 / denom + 0.5f;
    p0 = fminf(fmaxf(p0, 0.f), 1.f) * 4.f;
    p1 = fminf(fmaxf(p1, 0.f), 1.f) * 4.f;
    float b0 = fminf(floorf(p0), 3.f);
    float b1 = fminf(floorf(p1), 3.f);
    float f0 = p0 - b0, f1 = p1 - b1;
    int i0 = (int)b0, i1 = (int)b1;
    wsp[0] = (1.f - f0) * (1.f - f1); kks[0] = i0     + KDIM *  i1;
    wsp[1] =        f0  * (1.f - f1); kks[1] = i0 + 1 + KDIM *  i1;
    wsp[2] = (1.f - f0) *        f1 ; kks[2] = i0     + KDIM * (i1 + 1);
    wsp[3] =        f0  *        f1 ; kks[3] = i0 + 1 + KDIM * (i1 + 1);
}

// ---------------- amax over |pos[src]-pos[dst]| (all edges) ----------------
__global__ void amax0_k(const float* __restrict__ pos, const int* __restrict__ src,
                        const int* __restrict__ dst, int E, unsigned* __restrict__ amax){
    int e = blockIdx.x * 256 + threadIdx.x;
    float cand = 0.f;
    if (e < E){
        int s = src[e], d = dst[e];
        float c0 = pos[s*2]   - pos[d*2];
        float c1 = pos[s*2+1] - pos[d*2+1];
        cand = fmaxf(fabsf(c0), fabsf(c1));
    }
    __shared__ float sm[256];
    sm[threadIdx.x] = cand; __syncthreads();
    for (int o = 128; o > 0; o >>= 1){
        if (threadIdx.x < o) sm[threadIdx.x] = fmaxf(sm[threadIdx.x], sm[threadIdx.x + o]);
        __syncthreads();
    }
    if (threadIdx.x == 0 && sm[0] > 0.f) atomicMax(amax, __float_as_uint(sm[0]));
}

// ---------------- conv1 (Fin=1->32) + pool1 fused, one block per graph ----------------
// LDS: acc[75][25], deg[75], node x/pos, W1/r1/b1 staged, px[36][32] segment-max.
__global__ __launch_bounds__(256) void conv1pool1_k(
        const float* __restrict__ x, const float* __restrict__ pos,
        const int* __restrict__ src, const int* __restrict__ dst, int EPG,
        const unsigned* __restrict__ amaxp,
        const float* __restrict__ W1, const float* __restrict__ r1, const float* __restrict__ b1,
        float* __restrict__ px1, float* __restrict__ pp1, float* __restrict__ sv1,
        int* __restrict__ cl1){
    __shared__ float acc[NPG * 25];
    __shared__ float deg[NPG];
    __shared__ float xl[NPG], p0l[NPG], p1l[NPG];
    __shared__ int   cli[NPG];
    __shared__ float W1s[800], r1s[32], b1s[32];
    __shared__ unsigned px[36 * 32];
    __shared__ float cnt[36], ps[72];

    const int b = blockIdx.x, t = threadIdx.x;
    const int n0 = b * NPG, e0 = b * EPG;

    for (int i = t; i < NPG * 25; i += 256) acc[i] = 0.f;
    for (int i = t; i < 36 * 32; i += 256) px[i] = 0u;
    if (t < NPG) deg[t] = 0.f;
    if (t < 36) cnt[t] = 0.f;
    if (t < 72) ps[t] = 0.f;
    for (int i = t; i < 800; i += 256) W1s[i] = W1[i];
    if (t < 32){ r1s[t] = r1[t]; b1s[t] = b1[t]; }
    if (t < NPG){
        float p0 = pos[(n0 + t) * 2], p1 = pos[(n0 + t) * 2 + 1];
        xl[t] = x[n0 + t]; p0l[t] = p0; p1l[t] = p1;
        int c0 = min(max((int)floorf(p0 / 5.f), 0), 5);
        int c1 = min(max((int)floorf(p1 / 5.f), 0), 5);
        int c = c1 * 6 + c0;
        cli[t] = c;
        cl1[n0 + t] = b * 36 + c;
    }
    __syncthreads();
    if (t < NPG){
        int c = cli[t];
        atomicAdd(&cnt[c], 1.f);
        atomicAdd(&ps[c*2],     p0l[t]);
        atomicAdd(&ps[c*2 + 1], p1l[t]);
    }

    const float am = __uint_as_float(*amaxp);
    for (int e = t; e < EPG; e += 256){
        int s = src[e0 + e] - n0;
        int d = dst[e0 + e] - n0;
        float c0 = p0l[s] - p0l[d];
        float c1 = p1l[s] - p1l[d];
        int kks[4]; float wsp[4];
        spline2(c0, c1, am, kks, wsp);
        float xv = xl[s];
        #pragma unroll
        for (int c = 0; c < 4; c++) atomicAdd(&acc[d*25 + kks[c]], wsp[c] * xv);
        atomicAdd(&deg[d], 1.f);
    }
    __syncthreads();

    // transform + elu + pool-max
    for (int idx = t; idx < NPG * 32; idx += 256){
        int i = idx >> 5, o = idx & 31;
        float sum = 0.f;
        #pragma unroll
        for (int k = 0; k < 25; k++) sum += acc[i*25 + k] * W1s[k*32 + o];
        float v = sum / fmaxf(deg[i], 1.f) + xl[i] * r1s[o] + b1s[o];
        v = eluf(v);
        atomicMax(&px[cli[i]*32 + o], fenc(v));
    }
    __syncthreads();

    for (int idx = t; idx < 36 * 32; idx += 256){
        int s_ = idx >> 5;
        float c = cnt[s_];
        px1[(size_t)(b*36)*32 + idx] = (c > 0.f) ? fdec(px[idx]) : 0.f;
    }
    if (t < 36){
        float c = cnt[t], m = fmaxf(c, 1.f);
        pp1[(b*36 + t)*2]     = ps[t*2] / m;
        pp1[(b*36 + t)*2 + 1] = ps[t*2 + 1] / m;
        sv1[b*36 + t] = (c > 0.f) ? 1.f : 0.f;
    }
}

// ---------------- fused dedup + CSR build, one block per graph ----------------
// Remap edges via clmap, dedup (a,b) pairs via LDS pairmark (atomicMin edge id),
// per-cluster degree, scan, CSR fill. rowptr2[i*2]=start, [i*2+1]=end (global elist idx).
template<int GG>
__global__ __launch_bounds__(256) void dedup_csr_k(
        const int* src_in, const int* dst_in,
        const int* __restrict__ clmap, const unsigned char* __restrict__ kf_in,
        unsigned char* kf_out, int* es_out, int* ed_out,
        const float* __restrict__ pp, int EPG,
        int* __restrict__ elist, int* __restrict__ rowptr2, unsigned* __restrict__ amax){
    __shared__ unsigned pm[GG * GG];
    __shared__ float degs[GG];
    __shared__ int rs[GG + 1];
    __shared__ int cur[GG];
    __shared__ float red[256];

    const int b = blockIdx.x, t = threadIdx.x;
    const int e0 = b * EPG;
    const int cbase = b * GG;

    for (int i = t; i < GG * GG; i += 256) pm[i] = 0xFFFFFFFFu;
    if (t < GG) degs[t] = 0.f;
    __syncthreads();

    const int niter = (EPG + 255) / 256;   // <= 8 for EPG <= 2048
    int la[8], lb[8]; bool lm[8];
    for (int it = 0; it < niter; it++){
        int e = t + it * 256;
        lm[it] = false;
        if (e < EPG){
            int a  = clmap[src_in[e0 + e]];
            int bb = clmap[dst_in[e0 + e]];
            la[it] = a; lb[it] = bb;
            es_out[e0 + e] = a; ed_out[e0 + e] = bb;
            bool m = (kf_in ? (kf_in[e0 + e] != 0) : true) && (a != bb);
            lm[it] = m;
            if (m) atomicMin(&pm[(a - cbase) * GG + (bb - cbase)], (unsigned)e);
        }
    }
    __syncthreads();

    float cand = 0.f;
    bool kept[8];
    for (int it = 0; it < niter; it++){
        int e = t + it * 256;
        kept[it] = false;
        if (e < EPG){
            bool k = false;
            if (lm[it]){
                int key = (la[it] - cbase) * GG + (lb[it] - cbase);
                k = (pm[key] == (unsigned)e);
            }
            kept[it] = k;
            if (kf_out) kf_out[e0 + e] = k ? 1 : 0;
            if (k){
                atomicAdd(&degs[lb[it] - cbase], 1.f);
                float c0 = pp[la[it]*2]     - pp[lb[it]*2];
                float c1 = pp[la[it]*2 + 1] - pp[lb[it]*2 + 1];
                cand = fmaxf(cand, fmaxf(fabsf(c0), fabsf(c1)));
            }
        }
    }
    red[t] = cand; __syncthreads();
    for (int o = 128; o > 0; o >>= 1){
        if (t < o) red[t] = fmaxf(red[t], red[t + o]);
        __syncthreads();
    }
    if (t == 0){
        if (red[0] > 0.f) atomicMax(amax, __float_as_uint(red[0]));
        int run = 0;
        for (int i = 0; i < GG; i++){ rs[i] = run; run += (int)degs[i]; }
        rs[GG] = run;
    }
    __syncthreads();
    if (t < GG){
        rowptr2[(cbase + t)*2]     = e0 + rs[t];
        rowptr2[(cbase + t)*2 + 1] = e0 + rs[t + 1];
        cur[t] = rs[t];
    }
    __syncthreads();
    for (int it = 0; it < niter; it++){
        int e = t + it * 256;
        if (kept[it]){
            int slot = atomicAdd(&cur[lb[it] - cbase], 1);
            elist[e0 + slot] = e0 + e;
        }
    }
}

// ---------------- generic mid pooling (stage2), one block per graph ----------------
template<int CIN, int G>
__global__ __launch_bounds__(256) void pool_mid_k(
        const float* __restrict__ xin, const float* __restrict__ ppin,
        const float* __restrict__ svin, float size,
        float* __restrict__ pxout, float* __restrict__ ppout, float* __restrict__ svout,
        int* __restrict__ clout){
    __shared__ unsigned px[G * G * 64];
    __shared__ float cnt[G * G], ps[2 * G * G];
    __shared__ int cli[CIN];
    const int b = blockIdx.x, t = threadIdx.x;

    for (int i = t; i < G * G * 64; i += 256) px[i] = 0u;
    if (t < G * G){ cnt[t] = 0.f; ps[t*2] = 0.f; ps[t*2 + 1] = 0.f; }
    if (t < CIN){
        float v  = svin[b*CIN + t];
        float p0 = ppin[(b*CIN + t)*2], p1 = ppin[(b*CIN + t)*2 + 1];
        int c0 = min(max((int)floorf(p0 / size), 0), G - 1);
        int c1 = min(max((int)floorf(p1 / size), 0), G - 1);
        int c = c1 * G + c0;
        cli[t] = (v > 0.f) ? c : -1;
        clout[b*CIN + t] = b * G * G + c;
    }
    __syncthreads();
    if (t < CIN && cli[t] >= 0){
        int c = cli[t];
        atomicAdd(&cnt[c], 1.f);
        atomicAdd(&ps[c*2],     ppin[(b*CIN + t)*2]);
        atomicAdd(&ps[c*2 + 1], ppin[(b*CIN + t)*2 + 1]);
    }
    __syncthreads();
    for (int idx = t; idx < CIN * 64; idx += 256){
        int i = idx >> 6, f = idx & 63;
        if (cli[i] >= 0)
            atomicMax(&px[cli[i]*64 + f], fenc(xin[(size_t)(b*CIN + i)*64 + f]));
    }
    __syncthreads();
    for (int idx = t; idx < G * G * 64; idx += 256){
        int s_ = idx >> 6;
        pxout[(size_t)(b*G*G)*64 + idx] = (cnt[s_] > 0.f) ? fdec(px[idx]) : 0.f;
    }
    if (t < G * G){
        float c = cnt[t], m = fmaxf(c, 1.f);
        ppout[(b*G*G + t)*2]     = ps[t*2] / m;
        ppout[(b*G*G + t)*2 + 1] = ps[t*2 + 1] / m;
        svout[b*G*G + t] = (c > 0.f) ? 1.f : 0.f;
    }
}

// ---------------- W' = [W ; root] concat (K' = 26*FIN rows x 64 cols) ----------------
__global__ void wconcat_k(const float* __restrict__ W, const float* __restrict__ root,
                          int FIN, float* __restrict__ Wc){
    int i = blockIdx.x * 256 + threadIdx.x;
    int tot = 26 * FIN * 64;
    if (i >= tot) return;
    int k = i >> 6, c = i & 63;
    Wc[i] = (k < 25 * FIN) ? W[i] : root[(size_t)(k - 25 * FIN) * 64 + c];
}

// ---------------- conv2/conv3 phase A: CSR gather into LDS, dump A' rows ----------------
// A'[node] = [acc/deg (25*FIN) | x[node] (FIN)], stride 26*FIN.
template<int FIN>
__global__ __launch_bounds__(256) void conv_gather_k(
        const float* __restrict__ x, const float* __restrict__ ppos,
        const int* __restrict__ esrc, const int* __restrict__ elist,
        const int* __restrict__ rowptr2, const unsigned* __restrict__ amaxp,
        int n, float* __restrict__ Aout){
    constexpr int EPB = (FIN == 32) ? 2 : 1;
    constexpr int ACC = 25 * FIN;
    constexpr int KTOT = 26 * FIN;
    __shared__ float acc[4 * EPB * ACC];           // 25.6 KB
    int g = threadIdx.x >> 6, lane = threadIdx.x & 63;
    int node = blockIdx.x * 4 + g;
    float* accg = acc + g * EPB * ACC;

    for (int i = threadIdx.x; i < 4 * EPB * ACC; i += 256) acc[i] = 0.f;
    __syncthreads();

    int row0 = 0, row1 = 0;
    if (node < n){
        row0 = rowptr2[node*2]; row1 = rowptr2[node*2 + 1];
        float am = __uint_as_float(*amaxp);
        float pd0 = ppos[node*2], pd1 = ppos[node*2 + 1];
        int ebuf = (EPB == 2) ? (lane >> 5) : 0;
        int f = lane & (FIN - 1);
        float* ab = accg + ebuf * ACC;
        for (int i = row0 + ebuf; i < row1; i += EPB){
            int e = elist[i];
            int a = esrc[e];
            float c0 = ppos[a*2]     - pd0;
            float c1 = ppos[a*2 + 1] - pd1;
            int kks[4]; float wsp[4];
            spline2(c0, c1, am, kks, wsp);
            float xv = x[(size_t)a * FIN + f];
            #pragma unroll
            for (int c = 0; c < 4; c++) ab[kks[c] * FIN + f] += wsp[c] * xv;
        }
    }
    __syncthreads();

    if (node >= n) return;
    float inv = 1.f / (float)max(row1 - row0, 1);
    float4* dst4 = (float4*)(Aout + (size_t)node * KTOT);
    const float4* s4  = (const float4*)accg;
    const float4* s4b = (const float4*)(accg + ACC);
    #pragma unroll 2
    for (int j = lane; j < ACC / 4; j += 64){
        float4 v = s4[j];
        if (EPB == 2){
            float4 u = s4b[j];
            v.x += u.x; v.y += u.y; v.z += u.z; v.w += u.w;
        }
        v.x *= inv; v.y *= inv; v.z *= inv; v.w *= inv;
        dst4[j] = v;
    }
    const float4* x4 = (const float4*)(x + (size_t)node * FIN);
    for (int j = lane; j < FIN / 4; j += 64) dst4[ACC / 4 + j] = x4[j];
}

// ---------------- conv2/conv3 phase B: tiled SGEMM + fused bias/ELU ----------------
template<int FIN>
__global__ __launch_bounds__(256) void conv_sgemm_k(
        const float* __restrict__ A, const float* __restrict__ Wc,
        const float* __restrict__ bias, int M, float* __restrict__ out){
    constexpr int KTOT = 26 * FIN;
    __shared__ float As[32][64];   // [k][row]
    __shared__ float Ws[32][64];   // [k][col]
    const int t = threadIdx.x;
    const int m0 = blockIdx.x * 64;

    const int r0 = (t & 15) * 4;
    const int c0 = (t >> 4) * 4;

    float accr[4][4];
    #pragma unroll
    for (int i = 0; i < 4; i++)
        #pragma unroll
        for (int j = 0; j < 4; j++) accr[i][j] = 0.f;

    for (int ks = 0; ks < KTOT; ks += 32){
        float4 av[2], wv[2];
        #pragma unroll
        for (int i = 0; i < 2; i++){
            int idx = t + i * 256;            // 0..511
            int arow = idx >> 3, ak4 = idx & 7;
            av[i] = *(const float4*)&A[(size_t)(m0 + arow) * KTOT + ks + ak4 * 4];
            int wk = idx >> 4, wc4 = idx & 15;
            wv[i] = *(const float4*)&Wc[(size_t)(ks + wk) * 64 + wc4 * 4];
        }
        __syncthreads();
        #pragma unroll
        for (int i = 0; i < 2; i++){
            int idx = t + i * 256;
            int arow = idx >> 3, ak4 = idx & 7;
            As[ak4*4 + 0][arow] = av[i].x;
            As[ak4*4 + 1][arow] = av[i].y;
            As[ak4*4 + 2][arow] = av[i].z;
            As[ak4*4 + 3][arow] = av[i].w;
            int wk = idx >> 4, wc4 = idx & 15;
            *(float4*)&Ws[wk][wc4 * 4] = wv[i];
        }
        __syncthreads();
        #pragma unroll
        for (int k = 0; k < 32; k++){
            float4 a = *(const float4*)&As[k][r0];
            float4 b = *(const float4*)&Ws[k][c0];
            accr[0][0] = fmaf(a.x, b.x, accr[0][0]);
            accr[0][1] = fmaf(a.x, b.y, accr[0][1]);
            accr[0][2] = fmaf(a.x, b.z, accr[0][2]);
            accr[0][3] = fmaf(a.x, b.w, accr[0][3]);
            accr[1][0] = fmaf(a.y, b.x, accr[1][0]);
            accr[1][1] = fmaf(a.y, b.y, accr[1][1]);
            accr[1][2] = fmaf(a.y, b.z, accr[1][2]);
            accr[1][3] = fmaf(a.y, b.w, accr[1][3]);
            accr[2][0] = fmaf(a.z, b.x, accr[2][0]);
            accr[2][1] = fmaf(a.z, b.y, accr[2][1]);
            accr[2][2] = fmaf(a.z, b.z, accr[2][2]);
            accr[2][3] = fmaf(a.z, b.w, accr[2][3]);
            accr[3][0] = fmaf(a.w, b.x, accr[3][0]);
            accr[3][1] = fmaf(a.w, b.y, accr[3][1]);
            accr[3][2] = fmaf(a.w, b.z, accr[3][2]);
            accr[3][3] = fmaf(a.w, b.w, accr[3][3]);
        }
    }

    const float4 bi = *(const float4*)&bias[c0];
    #pragma unroll
    for (int i = 0; i < 4; i++){
        float4 v;
        v.x = eluf(accr[i][0] + bi.x);
        v.y = eluf(accr[i][1] + bi.y);
        v.z = eluf(accr[i][2] + bi.z);
        v.w = eluf(accr[i][3] + bi.w);
        *(float4*)&out[(size_t)(m0 + r0 + i) * 64 + c0] = v;
    }
}

// ---------------- final pool (size=14, G=2) + MLP head + log_softmax ----------------
__global__ __launch_bounds__(256) void final_k(
        const float* __restrict__ xin, const float* __restrict__ ppin,
        const float* __restrict__ svin,
        const float* __restrict__ fw1, const float* __restrict__ fb1,
        const float* __restrict__ fw2, const float* __restrict__ fb2,
        float* __restrict__ out){
    __shared__ unsigned px[4 * 64];
    __shared__ float cnt[4];
    __shared__ int cli[25];
    __shared__ float xr[256];
    __shared__ float h[128];
    __shared__ float lg[10];
    __shared__ float lse;
    const int b = blockIdx.x, t = threadIdx.x;

    if (t < 256) { if (t < 4*64) px[t] = 0u; }
    if (t < 4) cnt[t] = 0.f;
    if (t < 25){
        float v  = svin[b*25 + t];
        float p0 = ppin[(b*25 + t)*2], p1 = ppin[(b*25 + t)*2 + 1];
        int c0 = min(max((int)floorf(p0 / 14.f), 0), 1);
        int c1 = min(max((int)floorf(p1 / 14.f), 0), 1);
        int c = c1 * 2 + c0;
        cli[t] = (v > 0.f) ? c : -1;
    }
    __syncthreads();
    if (t < 25 && cli[t] >= 0) atomicAdd(&cnt[cli[t]], 1.f);
    __syncthreads();
    for (int idx = t; idx < 25 * 64; idx += 256){
        int i = idx >> 6, f = idx & 63;
        if (cli[i] >= 0)
            atomicMax(&px[cli[i]*64 + f], fenc(xin[(size_t)(b*25 + i)*64 + f]));
    }
    __syncthreads();
    xr[t] = (cnt[t >> 6] > 0.f) ? fdec(px[t]) : 0.f;
    __syncthreads();
    if (t < 128){
        float s = fb1[t];
        const float* wrow = fw1 + (size_t)t * 256;
        #pragma unroll 8
        for (int i = 0; i < 256; i++) s += xr[i] * wrow[i];
        h[t] = eluf(s);
    }
    __syncthreads();
    if (t < 10){
        float s2 = fb2[t];
        const float* w2 = fw2 + (size_t)t * 128;
        for (int j = 0; j < 128; j++) s2 += h[j] * w2[j];
        lg[t] = s2;
    }
    __syncthreads();
    if (t == 0){
        float m = lg[0];
        for (int c = 1; c < 10; c++) m = fmaxf(m, lg[c]);
        float se = 0.f;
        for (int c = 0; c < 10; c++) se += expf(lg[c] - m);
        lse = m + logf(se);
    }
    __syncthreads();
    if (t < 10) out[(size_t)b*10 + t] = lg[t] - lse;
}

extern "C" void kernel_launch(void* const* d_in, const int* in_sizes, int n_in,
                              void* d_out, int out_size, void* d_ws, size_t ws_size,
                              hipStream_t stream) {
    const float* x   = (const float*)d_in[0];
    const float* pos = (const float*)d_in[1];
    const int*   src = (const int*)d_in[2];
    const int*   dst = (const int*)d_in[3];
    const float* W1  = (const float*)d_in[4];
    const float* r1  = (const float*)d_in[5];
    const float* b1  = (const float*)d_in[6];
    const float* W2  = (const float*)d_in[7];
    const float* r2  = (const float*)d_in[8];
    const float* b2  = (const float*)d_in[9];
    const float* W3  = (const float*)d_in[10];
    const float* r3  = (const float*)d_in[11];
    const float* b3  = (const float*)d_in[12];
    const float* fw1 = (const float*)d_in[13];
    const float* fb1 = (const float*)d_in[14];
    const float* fw2 = (const float*)d_in[15];
    const float* fb2 = (const float*)d_in[16];
    float* out = (float*)d_out;

    const int N   = in_sizes[0];
    const int E   = in_sizes[2];
    const int B   = N / NPG;
    const int EPG = E / B;
    const int S1  = B * 36;
    const int S2  = B * 25;

    float* w = (float*)d_ws;
    size_t off = 0;
    auto alloc = [&](size_t nelem){ size_t o = off; off += (nelem + 63) & ~(size_t)63; return o; };

    size_t o_scal = alloc(4);                 // amax0, amax1, amax2 — only memset needed
    size_t o_px1  = alloc((size_t)S1 * 32);
    size_t o_pp1  = alloc((size_t)S1 * 2);
    size_t o_sv1  = alloc(S1);
    size_t o_cl1  = alloc(N);
    size_t o_kf1  = alloc((E + 3) / 4);
    size_t o_es1  = alloc(E);
    size_t o_ed1  = alloc(E);
    size_t o_el   = alloc(E);
    size_t o_rp2  = alloc((size_t)2 * S1);
    size_t o_rp3  = alloc((size_t)2 * S2);
    size_t o_out2 = alloc((size_t)S1 * 64);
    size_t o_cl2  = alloc(S1);
    size_t o_px2  = alloc((size_t)S2 * 64);
    size_t o_pp2  = alloc((size_t)S2 * 2);
    size_t o_sv2  = alloc(S2);
    size_t o_out3 = alloc((size_t)S2 * 64);
    size_t o_wc   = alloc((size_t)26 * 64 * 64);
    size_t accAelems = (size_t)S1 * 832 > (size_t)S2 * 1664 ? (size_t)S1 * 832 : (size_t)S2 * 1664;
    size_t o_accA = alloc(accAelems);

    hipMemsetAsync(w + o_scal, 0, 4 * sizeof(float), stream);

    unsigned* scal = (unsigned*)(w + o_scal);
    auto nb = [](long long t){ return (unsigned)((t + 255) / 256); };
    auto nb4 = [](long long t){ return (unsigned)((t + 3) / 4); };

    // stage 1: amax over original edges, then fused conv1+pool1 per graph
    amax0_k<<<nb(E), 256, 0, stream>>>(pos, src, dst, E, scal + 0);
    conv1pool1_k<<<B, 256, 0, stream>>>(x, pos, src, dst, EPG, scal + 0, W1, r1, b1,
                                        w + o_px1, w + o_pp1, w + o_sv1, (int*)(w + o_cl1));

    // stage-1 -> stage-2 graph: fused dedup + CSR per graph
    dedup_csr_k<36><<<B, 256, 0, stream>>>(
        src, dst, (int*)(w + o_cl1), nullptr,
        (unsigned char*)(w + o_kf1), (int*)(w + o_es1), (int*)(w + o_ed1),
        w + o_pp1, EPG, (int*)(w + o_el), (int*)(w + o_rp2), scal + 1);

    // conv2 (Fin=32 -> 64)
    wconcat_k<<<nb(26 * 32 * 64), 256, 0, stream>>>(W2, r2, 32, w + o_wc);
    conv_gather_k<32><<<nb4(S1), 256, 0, stream>>>(
        w + o_px1, w + o_pp1, (int*)(w + o_es1), (int*)(w + o_el), (int*)(w + o_rp2),
        scal + 1, S1, w + o_accA);
    conv_sgemm_k<32><<<S1 / 64, 256, 0, stream>>>(w + o_accA, w + o_wc, b2, S1, w + o_out2);

    // pool 2 (size=7, G=5)
    pool_mid_k<36, 5><<<B, 256, 0, stream>>>(
        w + o_out2, w + o_pp1, w + o_sv1, 7.f,
        w + o_px2, w + o_pp2, w + o_sv2, (int*)(w + o_cl2));

    // stage-2 -> stage-3 graph (in-place remap of es1/ed1)
    dedup_csr_k<25><<<B, 256, 0, stream>>>(
        (int*)(w + o_es1), (int*)(w + o_ed1), (int*)(w + o_cl2), (unsigned char*)(w + o_kf1),
        nullptr, (int*)(w + o_es1), (int*)(w + o_ed1),
        w + o_pp2, EPG, (int*)(w + o_el), (int*)(w + o_rp3), scal + 2);

    // conv3 (Fin=64 -> 64)
    wconcat_k<<<nb(26 * 64 * 64), 256, 0, stream>>>(W3, r3, 64, w + o_wc);
    conv_gather_k<64><<<nb4(S2), 256, 0, stream>>>(
        w + o_px2, w + o_pp2, (int*)(w + o_es1), (int*)(w + o_el), (int*)(w + o_rp3),
        scal + 2, S2, w + o_accA);
    conv_sgemm_k<64><<<S2 / 64, 256, 0, stream>>>(w + o_accA, w + o_wc, b3, S2, w + o_out3);

    // final pool + MLP + log_softmax, per graph
    final_k<<<B, 256, 0, stream>>>(w + o_out3, w + o_pp2, w + o_sv2,
                                   fw1, fb1, fw2, fb2, out);
}

// Round 7
// 695.229 us; speedup vs baseline: 2.7316x; 1.0502x over previous
//
#include <hip/hip_runtime.h>
#include <math.h>

#define NPG 75
#define KDIM 5

__device__ __forceinline__ float eluf(float v){ return v > 0.f ? v : expf(v) - 1.f; }

// order-preserving float <-> uint encoding (for atomicMax-based segment max)
__device__ __forceinline__ unsigned fenc(float f){
    unsigned u = __float_as_uint(f);
    return (u & 0x80000000u) ? ~u : (u | 0x80000000u);
}
__device__ __forceinline__ float fdec(unsigned u){
    return (u & 0x80000000u) ? __uint_as_float(u & 0x7FFFFFFFu) : __uint_as_float(~u);
}

// spline basis: pseudo = cart/(2*amax)+0.5, clip[0,1], *4; 4 corner weights + kernel ids
__device__ __forceinline__ void spline2(float c0, float c1, float am, int* kks, float* wsp){
    float denom = 2.f * fmaxf(am, 1e-12f);
    float p0 = c0 / denom + 0.5f;
    float p1 = c1 / denom + 0.5f;
    p0 = fminf(fmaxf(p0, 0.f), 1.f) * 4.f;
    p1 = fminf(fmaxf(p1, 0.f), 1.f) * 4.f;
    float b0 = fminf(floorf(p0), 3.f);
    float b1 = fminf(floorf(p1), 3.f);
    float f0 = p0 - b0, f1 = p1 - b1;
    int i0 = (int)b0, i1 = (int)b1;
    wsp[0] = (1.f - f0) * (1.f - f1); kks[0] = i0     + KDIM *  i1;
    wsp[1] =        f0  * (1.f - f1); kks[1] = i0 + 1 + KDIM *  i1;
    wsp[2] = (1.f - f0) *        f1 ; kks[2] = i0     + KDIM * (i1 + 1);
    wsp[3] =        f0  *        f1 ; kks[3] = i0 + 1 + KDIM * (i1 + 1);
}

// ---------------- amax over |pos[src]-pos[dst]| (all edges) ----------------
__global__ void amax0_k(const float* __restrict__ pos, const int* __restrict__ src,
                        const int* __restrict__ dst, int E, unsigned* __restrict__ amax){
    int e = blockIdx.x * 256 + threadIdx.x;
    float cand = 0.f;
    if (e < E){
        int s = src[e], d = dst[e];
        float c0 = pos[s*2]   - pos[d*2];
        float c1 = pos[s*2+1] - pos[d*2+1];
        cand = fmaxf(fabsf(c0), fabsf(c1));
    }
    __shared__ float sm[256];
    sm[threadIdx.x] = cand; __syncthreads();
    for (int o = 128; o > 0; o >>= 1){
        if (threadIdx.x < o) sm[threadIdx.x] = fmaxf(sm[threadIdx.x], sm[threadIdx.x + o]);
        __syncthreads();
    }
    if (threadIdx.x == 0 && sm[0] > 0.f) atomicMax(amax, __float_as_uint(sm[0]));
}

// ---------------- conv1 (Fin=1->32) + pool1 fused, one block per graph ----------------
__global__ __launch_bounds__(256) void conv1pool1_k(
        const float* __restrict__ x, const float* __restrict__ pos,
        const int* __restrict__ src, const int* __restrict__ dst, int EPG,
        const unsigned* __restrict__ amaxp,
        const float* __restrict__ W1, const float* __restrict__ r1, const float* __restrict__ b1,
        float* __restrict__ px1, float* __restrict__ pp1, float* __restrict__ sv1,
        int* __restrict__ cl1){
    __shared__ float acc[NPG * 25];
    __shared__ float deg[NPG];
    __shared__ float xl[NPG], p0l[NPG], p1l[NPG];
    __shared__ int   cli[NPG];
    __shared__ float W1s[800], r1s[32], b1s[32];
    __shared__ unsigned px[36 * 32];
    __shared__ float cnt[36], ps[72];

    const int b = blockIdx.x, t = threadIdx.x;
    const int n0 = b * NPG, e0 = b * EPG;

    for (int i = t; i < NPG * 25; i += 256) acc[i] = 0.f;
    for (int i = t; i < 36 * 32; i += 256) px[i] = 0u;
    if (t < NPG) deg[t] = 0.f;
    if (t < 36) cnt[t] = 0.f;
    if (t < 72) ps[t] = 0.f;
    for (int i = t; i < 800; i += 256) W1s[i] = W1[i];
    if (t < 32){ r1s[t] = r1[t]; b1s[t] = b1[t]; }
    if (t < NPG){
        float p0 = pos[(n0 + t) * 2], p1 = pos[(n0 + t) * 2 + 1];
        xl[t] = x[n0 + t]; p0l[t] = p0; p1l[t] = p1;
        int c0 = min(max((int)floorf(p0 / 5.f), 0), 5);
        int c1 = min(max((int)floorf(p1 / 5.f), 0), 5);
        int c = c1 * 6 + c0;
        cli[t] = c;
        cl1[n0 + t] = b * 36 + c;
    }
    __syncthreads();
    if (t < NPG){
        int c = cli[t];
        atomicAdd(&cnt[c], 1.f);
        atomicAdd(&ps[c*2],     p0l[t]);
        atomicAdd(&ps[c*2 + 1], p1l[t]);
    }

    const float am = __uint_as_float(*amaxp);
    for (int e = t; e < EPG; e += 256){
        int s = src[e0 + e] - n0;
        int d = dst[e0 + e] - n0;
        float c0 = p0l[s] - p0l[d];
        float c1 = p1l[s] - p1l[d];
        int kks[4]; float wsp[4];
        spline2(c0, c1, am, kks, wsp);
        float xv = xl[s];
        #pragma unroll
        for (int c = 0; c < 4; c++) atomicAdd(&acc[d*25 + kks[c]], wsp[c] * xv);
        atomicAdd(&deg[d], 1.f);
    }
    __syncthreads();

    // transform + elu + pool-max
    for (int idx = t; idx < NPG * 32; idx += 256){
        int i = idx >> 5, o = idx & 31;
        float sum = 0.f;
        #pragma unroll
        for (int k = 0; k < 25; k++) sum += acc[i*25 + k] * W1s[k*32 + o];
        float v = sum / fmaxf(deg[i], 1.f) + xl[i] * r1s[o] + b1s[o];
        v = eluf(v);
        atomicMax(&px[cli[i]*32 + o], fenc(v));
    }
    __syncthreads();

    for (int idx = t; idx < 36 * 32; idx += 256){
        int s_ = idx >> 5;
        float c = cnt[s_];
        px1[(size_t)(b*36)*32 + idx] = (c > 0.f) ? fdec(px[idx]) : 0.f;
    }
    if (t < 36){
        float c = cnt[t], m = fmaxf(c, 1.f);
        pp1[(b*36 + t)*2]     = ps[t*2] / m;
        pp1[(b*36 + t)*2 + 1] = ps[t*2 + 1] / m;
        sv1[b*36 + t] = (c > 0.f) ? 1.f : 0.f;
    }
}

// ---------------- fused dedup + CSR build, one block per graph ----------------
template<int GG>
__global__ __launch_bounds__(256) void dedup_csr_k(
        const int* src_in, const int* dst_in,
        const int* __restrict__ clmap, const unsigned char* __restrict__ kf_in,
        unsigned char* kf_out, int* es_out, int* ed_out,
        const float* __restrict__ pp, int EPG,
        int* __restrict__ elist, int* __restrict__ rowptr2, unsigned* __restrict__ amax){
    __shared__ unsigned pm[GG * GG];
    __shared__ float degs[GG];
    __shared__ int rs[GG + 1];
    __shared__ int cur[GG];
    __shared__ float red[256];

    const int b = blockIdx.x, t = threadIdx.x;
    const int e0 = b * EPG;
    const int cbase = b * GG;

    for (int i = t; i < GG * GG; i += 256) pm[i] = 0xFFFFFFFFu;
    if (t < GG) degs[t] = 0.f;
    __syncthreads();

    const int niter = (EPG + 255) / 256;   // <= 8 for EPG <= 2048
    int la[8], lb[8]; bool lm[8];
    for (int it = 0; it < niter; it++){
        int e = t + it * 256;
        lm[it] = false;
        if (e < EPG){
            int a  = clmap[src_in[e0 + e]];
            int bb = clmap[dst_in[e0 + e]];
            la[it] = a; lb[it] = bb;
            es_out[e0 + e] = a; ed_out[e0 + e] = bb;
            bool m = (kf_in ? (kf_in[e0 + e] != 0) : true) && (a != bb);
            lm[it] = m;
            if (m) atomicMin(&pm[(a - cbase) * GG + (bb - cbase)], (unsigned)e);
        }
    }
    __syncthreads();

    float cand = 0.f;
    bool kept[8];
    for (int it = 0; it < niter; it++){
        int e = t + it * 256;
        kept[it] = false;
        if (e < EPG){
            bool k = false;
            if (lm[it]){
                int key = (la[it] - cbase) * GG + (lb[it] - cbase);
                k = (pm[key] == (unsigned)e);
            }
            kept[it] = k;
            if (kf_out) kf_out[e0 + e] = k ? 1 : 0;
            if (k){
                atomicAdd(&degs[lb[it] - cbase], 1.f);
                float c0 = pp[la[it]*2]     - pp[lb[it]*2];
                float c1 = pp[la[it]*2 + 1] - pp[lb[it]*2 + 1];
                cand = fmaxf(cand, fmaxf(fabsf(c0), fabsf(c1)));
            }
        }
    }
    red[t] = cand; __syncthreads();
    for (int o = 128; o > 0; o >>= 1){
        if (t < o) red[t] = fmaxf(red[t], red[t + o]);
        __syncthreads();
    }
    if (t == 0){
        if (red[0] > 0.f) atomicMax(amax, __float_as_uint(red[0]));
        int run = 0;
        for (int i = 0; i < GG; i++){ rs[i] = run; run += (int)degs[i]; }
        rs[GG] = run;
    }
    __syncthreads();
    if (t < GG){
        rowptr2[(cbase + t)*2]     = e0 + rs[t];
        rowptr2[(cbase + t)*2 + 1] = e0 + rs[t + 1];
        cur[t] = rs[t];
    }
    __syncthreads();
    for (int it = 0; it < niter; it++){
        int e = t + it * 256;
        if (kept[it]){
            int slot = atomicAdd(&cur[lb[it] - cbase], 1);
            elist[e0 + slot] = e0 + e;
        }
    }
}

// ---------------- generic mid pooling (stage2), one block per graph ----------------
template<int CIN, int G>
__global__ __launch_bounds__(256) void pool_mid_k(
        const float* __restrict__ xin, const float* __restrict__ ppin,
        const float* __restrict__ svin, float size,
        float* __restrict__ pxout, float* __restrict__ ppout, float* __restrict__ svout,
        int* __restrict__ clout){
    __shared__ unsigned px[G * G * 64];
    __shared__ float cnt[G * G], ps[2 * G * G];
    __shared__ int cli[CIN];
    const int b = blockIdx.x, t = threadIdx.x;

    for (int i = t; i < G * G * 64; i += 256) px[i] = 0u;
    if (t < G * G){ cnt[t] = 0.f; ps[t*2] = 0.f; ps[t*2 + 1] = 0.f; }
    if (t < CIN){
        float v  = svin[b*CIN + t];
        float p0 = ppin[(b*CIN + t)*2], p1 = ppin[(b*CIN + t)*2 + 1];
        int c0 = min(max((int)floorf(p0 / size), 0), G - 1);
        int c1 = min(max((int)floorf(p1 / size), 0), G - 1);
        int c = c1 * G + c0;
        cli[t] = (v > 0.f) ? c : -1;
        clout[b*CIN + t] = b * G * G + c;
    }
    __syncthreads();
    if (t < CIN && cli[t] >= 0){
        int c = cli[t];
        atomicAdd(&cnt[c], 1.f);
        atomicAdd(&ps[c*2],     ppin[(b*CIN + t)*2]);
        atomicAdd(&ps[c*2 + 1], ppin[(b*CIN + t)*2 + 1]);
    }
    __syncthreads();
    for (int idx = t; idx < CIN * 64; idx += 256){
        int i = idx >> 6, f = idx & 63;
        if (cli[i] >= 0)
            atomicMax(&px[cli[i]*64 + f], fenc(xin[(size_t)(b*CIN + i)*64 + f]));
    }
    __syncthreads();
    for (int idx = t; idx < G * G * 64; idx += 256){
        int s_ = idx >> 6;
        pxout[(size_t)(b*G*G)*64 + idx] = (cnt[s_] > 0.f) ? fdec(px[idx]) : 0.f;
    }
    if (t < G * G){
        float c = cnt[t], m = fmaxf(c, 1.f);
        ppout[(b*G*G + t)*2]     = ps[t*2] / m;
        ppout[(b*G*G + t)*2 + 1] = ps[t*2 + 1] / m;
        svout[b*G*G + t] = (c > 0.f) ? 1.f : 0.f;
    }
}

// ---------------- W' = [W ; root] concat (K' = 26*FIN rows x 64 cols) ----------------
__global__ void wconcat_k(const float* __restrict__ W, const float* __restrict__ root,
                          int FIN, float* __restrict__ Wc){
    int i = blockIdx.x * 256 + threadIdx.x;
    int tot = 26 * FIN * 64;
    if (i >= tot) return;
    int k = i >> 6, c = i & 63;
    Wc[i] = (k < 25 * FIN) ? W[i] : root[(size_t)(k - 25 * FIN) * 64 + c];
}

// ---------------- conv2/conv3 phase A: CSR gather into LDS, dump A' rows ----------------
// A'[node] = [acc/deg (25*FIN) | x[node] (FIN)], stride 26*FIN.
template<int FIN>
__global__ __launch_bounds__(256) void conv_gather_k(
        const float* __restrict__ x, const float* __restrict__ ppos,
        const int* __restrict__ esrc, const int* __restrict__ elist,
        const int* __restrict__ rowptr2, const unsigned* __restrict__ amaxp,
        int n, float* __restrict__ Aout){
    constexpr int EPB = (FIN == 32) ? 2 : 1;
    constexpr int ACC = 25 * FIN;
    constexpr int KTOT = 26 * FIN;
    __shared__ float acc[4 * EPB * ACC];           // 25.6 KB
    int g = threadIdx.x >> 6, lane = threadIdx.x & 63;
    int node = blockIdx.x * 4 + g;
    float* accg = acc + g * EPB * ACC;

    for (int i = threadIdx.x; i < 4 * EPB * ACC; i += 256) acc[i] = 0.f;
    __syncthreads();

    int row0 = 0, row1 = 0;
    if (node < n){
        row0 = rowptr2[node*2]; row1 = rowptr2[node*2 + 1];
        float am = __uint_as_float(*amaxp);
        float pd0 = ppos[node*2], pd1 = ppos[node*2 + 1];
        int ebuf = (EPB == 2) ? (lane >> 5) : 0;
        int f = lane & (FIN - 1);
        float* ab = accg + ebuf * ACC;
        for (int i = row0 + ebuf; i < row1; i += EPB){
            int e = elist[i];
            int a = esrc[e];
            float c0 = ppos[a*2]     - pd0;
            float c1 = ppos[a*2 + 1] - pd1;
            int kks[4]; float wsp[4];
            spline2(c0, c1, am, kks, wsp);
            float xv = x[(size_t)a * FIN + f];
            #pragma unroll
            for (int c = 0; c < 4; c++) ab[kks[c] * FIN + f] += wsp[c] * xv;
        }
    }
    __syncthreads();

    if (node >= n) return;
    float inv = 1.f / (float)max(row1 - row0, 1);
    float4* dst4 = (float4*)(Aout + (size_t)node * KTOT);
    const float4* s4  = (const float4*)accg;
    const float4* s4b = (const float4*)(accg + ACC);
    #pragma unroll 2
    for (int j = lane; j < ACC / 4; j += 64){
        float4 v = s4[j];
        if (EPB == 2){
            float4 u = s4b[j];
            v.x += u.x; v.y += u.y; v.z += u.z; v.w += u.w;
        }
        v.x *= inv; v.y *= inv; v.z *= inv; v.w *= inv;
        dst4[j] = v;
    }
    const float4* x4 = (const float4*)(x + (size_t)node * FIN);
    for (int j = lane; j < FIN / 4; j += 64) dst4[ACC / 4 + j] = x4[j];
}

// ---------------- conv2/conv3 phase B: tiled SGEMM, split-K partials ----------------
// Cpart[gy][M][64] = A'[M][kseg] x Wc[kseg][64]. Tile 64x64, 256 thr, 4x4/thread.
// As padded stride 68 to break the transpose-scatter bank clash (64-stride -> 8 banks).
template<int FIN, int SPLITK>
__global__ __launch_bounds__(256) void conv_sgemm_k(
        const float* __restrict__ A, const float* __restrict__ Wc,
        int M, float* __restrict__ Cpart){
    constexpr int KTOT = 26 * FIN;
    constexpr int KSEG = KTOT / SPLITK;   // must be multiple of 32 (416 for both convs)
    __shared__ float As[32 * 68];  // [k][row], stride 68
    __shared__ float Ws[32][64];   // [k][col]
    const int t = threadIdx.x;
    const int m0 = blockIdx.x * 64;
    const int kbeg = blockIdx.y * KSEG;

    const int r0 = (t & 15) * 4;
    const int c0 = (t >> 4) * 4;

    float accr[4][4];
    #pragma unroll
    for (int i = 0; i < 4; i++)
        #pragma unroll
        for (int j = 0; j < 4; j++) accr[i][j] = 0.f;

    for (int ks = 0; ks < KSEG; ks += 32){
        float4 av[2], wv[2];
        #pragma unroll
        for (int i = 0; i < 2; i++){
            int idx = t + i * 256;            // 0..511
            int arow = idx >> 3, ak4 = idx & 7;
            av[i] = *(const float4*)&A[(size_t)(m0 + arow) * KTOT + kbeg + ks + ak4 * 4];
            int wk = idx >> 4, wc4 = idx & 15;
            wv[i] = *(const float4*)&Wc[(size_t)(kbeg + ks + wk) * 64 + wc4 * 4];
        }
        __syncthreads();
        #pragma unroll
        for (int i = 0; i < 2; i++){
            int idx = t + i * 256;
            int arow = idx >> 3, ak4 = idx & 7;
            As[(ak4*4 + 0) * 68 + arow] = av[i].x;
            As[(ak4*4 + 1) * 68 + arow] = av[i].y;
            As[(ak4*4 + 2) * 68 + arow] = av[i].z;
            As[(ak4*4 + 3) * 68 + arow] = av[i].w;
            int wk = idx >> 4, wc4 = idx & 15;
            *(float4*)&Ws[wk][wc4 * 4] = wv[i];
        }
        __syncthreads();
        #pragma unroll
        for (int k = 0; k < 32; k++){
            float4 a = *(const float4*)&As[k * 68 + r0];
            float4 b = *(const float4*)&Ws[k][c0];
            accr[0][0] = fmaf(a.x, b.x, accr[0][0]);
            accr[0][1] = fmaf(a.x, b.y, accr[0][1]);
            accr[0][2] = fmaf(a.x, b.z, accr[0][2]);
            accr[0][3] = fmaf(a.x, b.w, accr[0][3]);
            accr[1][0] = fmaf(a.y, b.x, accr[1][0]);
            accr[1][1] = fmaf(a.y, b.y, accr[1][1]);
            accr[1][2] = fmaf(a.y, b.z, accr[1][2]);
            accr[1][3] = fmaf(a.y, b.w, accr[1][3]);
            accr[2][0] = fmaf(a.z, b.x, accr[2][0]);
            accr[2][1] = fmaf(a.z, b.y, accr[2][1]);
            accr[2][2] = fmaf(a.z, b.z, accr[2][2]);
            accr[2][3] = fmaf(a.z, b.w, accr[2][3]);
            accr[3][0] = fmaf(a.w, b.x, accr[3][0]);
            accr[3][1] = fmaf(a.w, b.y, accr[3][1]);
            accr[3][2] = fmaf(a.w, b.z, accr[3][2]);
            accr[3][3] = fmaf(a.w, b.w, accr[3][3]);
        }
    }

    float* cp = Cpart + ((size_t)blockIdx.y * M + m0) * 64;
    #pragma unroll
    for (int i = 0; i < 4; i++){
        float4 v = make_float4(accr[i][0], accr[i][1], accr[i][2], accr[i][3]);
        *(float4*)&cp[(size_t)(r0 + i) * 64 + c0] = v;
    }
}

// ---------------- conv epilogue: combine split-K partials + bias + ELU ----------------
template<int SPLITK>
__global__ void conv_epi_k(const float* __restrict__ Cpart, const float* __restrict__ bias,
                           int M, float* __restrict__ out){
    int gid = blockIdx.x * 256 + threadIdx.x;
    if (gid >= M * 64) return;
    int c = gid & 63;
    float v = bias[c];
    #pragma unroll
    for (int s = 0; s < SPLITK; s++) v += Cpart[(size_t)s * M * 64 + gid];
    out[gid] = eluf(v);
}

// ---------------- final pool (size=14, G=2) + MLP head + log_softmax ----------------
__global__ __launch_bounds__(256) void final_k(
        const float* __restrict__ xin, const float* __restrict__ ppin,
        const float* __restrict__ svin,
        const float* __restrict__ fw1, const float* __restrict__ fb1,
        const float* __restrict__ fw2, const float* __restrict__ fb2,
        float* __restrict__ out){
    __shared__ unsigned px[4 * 64];
    __shared__ float cnt[4];
    __shared__ int cli[25];
    __shared__ float xr[256];
    __shared__ float h[128];
    __shared__ float lg[10];
    __shared__ float lse;
    const int b = blockIdx.x, t = threadIdx.x;

    if (t < 256) { if (t < 4*64) px[t] = 0u; }
    if (t < 4) cnt[t] = 0.f;
    if (t < 25){
        float v  = svin[b*25 + t];
        float p0 = ppin[(b*25 + t)*2], p1 = ppin[(b*25 + t)*2 + 1];
        int c0 = min(max((int)floorf(p0 / 14.f), 0), 1);
        int c1 = min(max((int)floorf(p1 / 14.f), 0), 1);
        int c = c1 * 2 + c0;
        cli[t] = (v > 0.f) ? c : -1;
    }
    __syncthreads();
    if (t < 25 && cli[t] >= 0) atomicAdd(&cnt[cli[t]], 1.f);
    __syncthreads();
    for (int idx = t; idx < 25 * 64; idx += 256){
        int i = idx >> 6, f = idx & 63;
        if (cli[i] >= 0)
            atomicMax(&px[cli[i]*64 + f], fenc(xin[(size_t)(b*25 + i)*64 + f]));
    }
    __syncthreads();
    xr[t] = (cnt[t >> 6] > 0.f) ? fdec(px[t]) : 0.f;
    __syncthreads();
    if (t < 128){
        float s = fb1[t];
        const float* wrow = fw1 + (size_t)t * 256;
        #pragma unroll 8
        for (int i = 0; i < 256; i++) s += xr[i] * wrow[i];
        h[t] = eluf(s);
    }
    __syncthreads();
    if (t < 10){
        float s2 = fb2[t];
        const float* w2 = fw2 + (size_t)t * 128;
        for (int j = 0; j < 128; j++) s2 += h[j] * w2[j];
        lg[t] = s2;
    }
    __syncthreads();
    if (t == 0){
        float m = lg[0];
        for (int c = 1; c < 10; c++) m = fmaxf(m, lg[c]);
        float se = 0.f;
        for (int c = 0; c < 10; c++) se += expf(lg[c] - m);
        lse = m + logf(se);
    }
    __syncthreads();
    if (t < 10) out[(size_t)b*10 + t] = lg[t] - lse;
}

extern "C" void kernel_launch(void* const* d_in, const int* in_sizes, int n_in,
                              void* d_out, int out_size, void* d_ws, size_t ws_size,
                              hipStream_t stream) {
    const float* x   = (const float*)d_in[0];
    const float* pos = (const float*)d_in[1];
    const int*   src = (const int*)d_in[2];
    const int*   dst = (const int*)d_in[3];
    const float* W1  = (const float*)d_in[4];
    const float* r1  = (const float*)d_in[5];
    const float* b1  = (const float*)d_in[6];
    const float* W2  = (const float*)d_in[7];
    const float* r2  = (const float*)d_in[8];
    const float* b2  = (const float*)d_in[9];
    const float* W3  = (const float*)d_in[10];
    const float* r3  = (const float*)d_in[11];
    const float* b3  = (const float*)d_in[12];
    const float* fw1 = (const float*)d_in[13];
    const float* fb1 = (const float*)d_in[14];
    const float* fw2 = (const float*)d_in[15];
    const float* fb2 = (const float*)d_in[16];
    float* out = (float*)d_out;

    const int N   = in_sizes[0];
    const int E   = in_sizes[2];
    const int B   = N / NPG;
    const int EPG = E / B;
    const int S1  = B * 36;
    const int S2  = B * 25;

    float* w = (float*)d_ws;
    size_t off = 0;
    auto alloc = [&](size_t nelem){ size_t o = off; off += (nelem + 63) & ~(size_t)63; return o; };

    size_t o_scal = alloc(4);                 // amax0, amax1, amax2 — only memset needed
    size_t o_px1  = alloc((size_t)S1 * 32);
    size_t o_pp1  = alloc((size_t)S1 * 2);
    size_t o_sv1  = alloc(S1);
    size_t o_cl1  = alloc(N);
    size_t o_kf1  = alloc((E + 3) / 4);
    size_t o_es1  = alloc(E);
    size_t o_ed1  = alloc(E);
    size_t o_el   = alloc(E);
    size_t o_rp2  = alloc((size_t)2 * S1);
    size_t o_rp3  = alloc((size_t)2 * S2);
    size_t o_out2 = alloc((size_t)S1 * 64);
    size_t o_cl2  = alloc(S1);
    size_t o_px2  = alloc((size_t)S2 * 64);
    size_t o_pp2  = alloc((size_t)S2 * 2);
    size_t o_sv2  = alloc(S2);
    size_t o_out3 = alloc((size_t)S2 * 64);
    size_t o_wc   = alloc((size_t)26 * 64 * 64);
    size_t cpElems = (size_t)2 * S1 * 64 > (size_t)4 * S2 * 64 ? (size_t)2 * S1 * 64 : (size_t)4 * S2 * 64;
    size_t o_cp   = alloc(cpElems);           // split-K partials (union of conv2/conv3)
    size_t accAelems = (size_t)S1 * 832 > (size_t)S2 * 1664 ? (size_t)S1 * 832 : (size_t)S2 * 1664;
    size_t o_accA = alloc(accAelems);

    hipMemsetAsync(w + o_scal, 0, 4 * sizeof(float), stream);

    unsigned* scal = (unsigned*)(w + o_scal);
    auto nb = [](long long t){ return (unsigned)((t + 255) / 256); };
    auto nb4 = [](long long t){ return (unsigned)((t + 3) / 4); };

    // stage 1: amax over original edges, then fused conv1+pool1 per graph
    amax0_k<<<nb(E), 256, 0, stream>>>(pos, src, dst, E, scal + 0);
    conv1pool1_k<<<B, 256, 0, stream>>>(x, pos, src, dst, EPG, scal + 0, W1, r1, b1,
                                        w + o_px1, w + o_pp1, w + o_sv1, (int*)(w + o_cl1));

    // stage-1 -> stage-2 graph: fused dedup + CSR per graph
    dedup_csr_k<36><<<B, 256, 0, stream>>>(
        src, dst, (int*)(w + o_cl1), nullptr,
        (unsigned char*)(w + o_kf1), (int*)(w + o_es1), (int*)(w + o_ed1),
        w + o_pp1, EPG, (int*)(w + o_el), (int*)(w + o_rp2), scal + 1);

    // conv2 (Fin=32 -> 64), split-K = 2
    wconcat_k<<<nb(26 * 32 * 64), 256, 0, stream>>>(W2, r2, 32, w + o_wc);
    conv_gather_k<32><<<nb4(S1), 256, 0, stream>>>(
        w + o_px1, w + o_pp1, (int*)(w + o_es1), (int*)(w + o_el), (int*)(w + o_rp2),
        scal + 1, S1, w + o_accA);
    {
        dim3 g(S1 / 64, 2);
        conv_sgemm_k<32, 2><<<g, 256, 0, stream>>>(w + o_accA, w + o_wc, S1, w + o_cp);
    }
    conv_epi_k<2><<<nb((long long)S1 * 64), 256, 0, stream>>>(w + o_cp, b2, S1, w + o_out2);

    // pool 2 (size=7, G=5)
    pool_mid_k<36, 5><<<B, 256, 0, stream>>>(
        w + o_out2, w + o_pp1, w + o_sv1, 7.f,
        w + o_px2, w + o_pp2, w + o_sv2, (int*)(w + o_cl2));

    // stage-2 -> stage-3 graph (in-place remap of es1/ed1)
    dedup_csr_k<25><<<B, 256, 0, stream>>>(
        (int*)(w + o_es1), (int*)(w + o_ed1), (int*)(w + o_cl2), (unsigned char*)(w + o_kf1),
        nullptr, (int*)(w + o_es1), (int*)(w + o_ed1),
        w + o_pp2, EPG, (int*)(w + o_el), (int*)(w + o_rp3), scal + 2);

    // conv3 (Fin=64 -> 64), split-K = 4
    wconcat_k<<<nb(26 * 64 * 64), 256, 0, stream>>>(W3, r3, 64, w + o_wc);
    conv_gather_k<64><<<nb4(S2), 256, 0, stream>>>(
        w + o_px2, w + o_pp2, (int*)(w + o_es1), (int*)(w + o_el), (int*)(w + o_rp3),
        scal + 2, S2, w + o_accA);
    {
        dim3 g(S2 / 64, 4);
        conv_sgemm_k<64, 4><<<g, 256, 0, stream>>>(w + o_accA, w + o_wc, S2, w + o_cp);
    }
    conv_epi_k<4><<<nb((long long)S2 * 64), 256, 0, stream>>>(w + o_cp, b3, S2, w + o_out3);

    // final pool + MLP + log_softmax, per graph
    final_k<<<B, 256, 0, stream>>>(w + o_out3, w + o_pp2, w + o_sv2,
                                   fw1, fb1, fw2, fb2, out);
}

// Round 8
// 586.161 us; speedup vs baseline: 3.2398x; 1.1861x over previous
//
#include <hip/hip_runtime.h>
#include <math.h>

#define NPG 75
#define KDIM 5

typedef _Float16 half8 __attribute__((ext_vector_type(8)));
typedef _Float16 half4 __attribute__((ext_vector_type(4)));
typedef float f32x4 __attribute__((ext_vector_type(4)));

__device__ __forceinline__ float eluf(float v){ return v > 0.f ? v : expf(v) - 1.f; }

// order-preserving float <-> uint encoding (for atomicMax-based segment max)
__device__ __forceinline__ unsigned fenc(float f){
    unsigned u = __float_as_uint(f);
    return (u & 0x80000000u) ? ~u : (u | 0x80000000u);
}
__device__ __forceinline__ float fdec(unsigned u){
    return (u & 0x80000000u) ? __uint_as_float(u & 0x7FFFFFFFu) : __uint_as_float(~u);
}

// spline basis: pseudo = cart/(2*amax)+0.5, clip[0,1], *4; 4 corner weights + kernel ids
__device__ __forceinline__ void spline2(float c0, float c1, float am, int* kks, float* wsp){
    float denom = 2.f * fmaxf(am, 1e-12f);
    float p0 = c0 / denom + 0.5f;
    float p1 = c1 / denom + 0.5f;
    p0 = fminf(fmaxf(p0, 0.f), 1.f) * 4.f;
    p1 = fminf(fmaxf(p1, 0.f), 1.f) * 4.f;
    float b0 = fminf(floorf(p0), 3.f);
    float b1 = fminf(floorf(p1), 3.f);
    float f0 = p0 - b0, f1 = p1 - b1;
    int i0 = (int)b0, i1 = (int)b1;
    wsp[0] = (1.f - f0) * (1.f - f1); kks[0] = i0     + KDIM *  i1;
    wsp[1] =        f0  * (1.f - f1); kks[1] = i0 + 1 + KDIM *  i1;
    wsp[2] = (1.f - f0) *        f1 ; kks[2] = i0     + KDIM * (i1 + 1);
    wsp[3] =        f0  *        f1 ; kks[3] = i0 + 1 + KDIM * (i1 + 1);
}

// ---------------- amax over |pos[src]-pos[dst]| (all edges) ----------------
__global__ void amax0_k(const float* __restrict__ pos, const int* __restrict__ src,
                        const int* __restrict__ dst, int E, unsigned* __restrict__ amax){
    int e = blockIdx.x * 256 + threadIdx.x;
    float cand = 0.f;
    if (e < E){
        int s = src[e], d = dst[e];
        float c0 = pos[s*2]   - pos[d*2];
        float c1 = pos[s*2+1] - pos[d*2+1];
        cand = fmaxf(fabsf(c0), fabsf(c1));
    }
    __shared__ float sm[256];
    sm[threadIdx.x] = cand; __syncthreads();
    for (int o = 128; o > 0; o >>= 1){
        if (threadIdx.x < o) sm[threadIdx.x] = fmaxf(sm[threadIdx.x], sm[threadIdx.x + o]);
        __syncthreads();
    }
    if (threadIdx.x == 0 && sm[0] > 0.f) atomicMax(amax, __float_as_uint(sm[0]));
}

// ---------------- conv1 (Fin=1->32) + pool1 fused, one block per graph ----------------
__global__ __launch_bounds__(256) void conv1pool1_k(
        const float* __restrict__ x, const float* __restrict__ pos,
        const int* __restrict__ src, const int* __restrict__ dst, int EPG,
        const unsigned* __restrict__ amaxp,
        const float* __restrict__ W1, const float* __restrict__ r1, const float* __restrict__ b1,
        float* __restrict__ px1, float* __restrict__ pp1, float* __restrict__ sv1,
        int* __restrict__ cl1){
    __shared__ float acc[NPG * 25];
    __shared__ float deg[NPG];
    __shared__ float xl[NPG], p0l[NPG], p1l[NPG];
    __shared__ int   cli[NPG];
    __shared__ float W1s[800], r1s[32], b1s[32];
    __shared__ unsigned px[36 * 32];
    __shared__ float cnt[36], ps[72];

    const int b = blockIdx.x, t = threadIdx.x;
    const int n0 = b * NPG, e0 = b * EPG;

    for (int i = t; i < NPG * 25; i += 256) acc[i] = 0.f;
    for (int i = t; i < 36 * 32; i += 256) px[i] = 0u;
    if (t < NPG) deg[t] = 0.f;
    if (t < 36) cnt[t] = 0.f;
    if (t < 72) ps[t] = 0.f;
    for (int i = t; i < 800; i += 256) W1s[i] = W1[i];
    if (t < 32){ r1s[t] = r1[t]; b1s[t] = b1[t]; }
    if (t < NPG){
        float p0 = pos[(n0 + t) * 2], p1 = pos[(n0 + t) * 2 + 1];
        xl[t] = x[n0 + t]; p0l[t] = p0; p1l[t] = p1;
        int c0 = min(max((int)floorf(p0 / 5.f), 0), 5);
        int c1 = min(max((int)floorf(p1 / 5.f), 0), 5);
        int c = c1 * 6 + c0;
        cli[t] = c;
        cl1[n0 + t] = b * 36 + c;
    }
    __syncthreads();
    if (t < NPG){
        int c = cli[t];
        atomicAdd(&cnt[c], 1.f);
        atomicAdd(&ps[c*2],     p0l[t]);
        atomicAdd(&ps[c*2 + 1], p1l[t]);
    }

    const float am = __uint_as_float(*amaxp);
    for (int e = t; e < EPG; e += 256){
        int s = src[e0 + e] - n0;
        int d = dst[e0 + e] - n0;
        float c0 = p0l[s] - p0l[d];
        float c1 = p1l[s] - p1l[d];
        int kks[4]; float wsp[4];
        spline2(c0, c1, am, kks, wsp);
        float xv = xl[s];
        #pragma unroll
        for (int c = 0; c < 4; c++) atomicAdd(&acc[d*25 + kks[c]], wsp[c] * xv);
        atomicAdd(&deg[d], 1.f);
    }
    __syncthreads();

    // transform + elu + pool-max
    for (int idx = t; idx < NPG * 32; idx += 256){
        int i = idx >> 5, o = idx & 31;
        float sum = 0.f;
        #pragma unroll
        for (int k = 0; k < 25; k++) sum += acc[i*25 + k] * W1s[k*32 + o];
        float v = sum / fmaxf(deg[i], 1.f) + xl[i] * r1s[o] + b1s[o];
        v = eluf(v);
        atomicMax(&px[cli[i]*32 + o], fenc(v));
    }
    __syncthreads();

    for (int idx = t; idx < 36 * 32; idx += 256){
        int s_ = idx >> 5;
        float c = cnt[s_];
        px1[(size_t)(b*36)*32 + idx] = (c > 0.f) ? fdec(px[idx]) : 0.f;
    }
    if (t < 36){
        float c = cnt[t], m = fmaxf(c, 1.f);
        pp1[(b*36 + t)*2]     = ps[t*2] / m;
        pp1[(b*36 + t)*2 + 1] = ps[t*2 + 1] / m;
        sv1[b*36 + t] = (c > 0.f) ? 1.f : 0.f;
    }
}

// ---------------- fused dedup + CSR build, one block per graph ----------------
template<int GG>
__global__ __launch_bounds__(256) void dedup_csr_k(
        const int* src_in, const int* dst_in,
        const int* __restrict__ clmap, const unsigned char* __restrict__ kf_in,
        unsigned char* kf_out, int* es_out, int* ed_out,
        const float* __restrict__ pp, int EPG,
        int* __restrict__ elist, int* __restrict__ rowptr2, unsigned* __restrict__ amax){
    __shared__ unsigned pm[GG * GG];
    __shared__ float degs[GG];
    __shared__ int rs[GG + 1];
    __shared__ int cur[GG];
    __shared__ float red[256];

    const int b = blockIdx.x, t = threadIdx.x;
    const int e0 = b * EPG;
    const int cbase = b * GG;

    for (int i = t; i < GG * GG; i += 256) pm[i] = 0xFFFFFFFFu;
    if (t < GG) degs[t] = 0.f;
    __syncthreads();

    const int niter = (EPG + 255) / 256;   // <= 8 for EPG <= 2048
    int la[8], lb[8]; bool lm[8];
    for (int it = 0; it < niter; it++){
        int e = t + it * 256;
        lm[it] = false;
        if (e < EPG){
            int a  = clmap[src_in[e0 + e]];
            int bb = clmap[dst_in[e0 + e]];
            la[it] = a; lb[it] = bb;
            es_out[e0 + e] = a; ed_out[e0 + e] = bb;
            bool m = (kf_in ? (kf_in[e0 + e] != 0) : true) && (a != bb);
            lm[it] = m;
            if (m) atomicMin(&pm[(a - cbase) * GG + (bb - cbase)], (unsigned)e);
        }
    }
    __syncthreads();

    float cand = 0.f;
    bool kept[8];
    for (int it = 0; it < niter; it++){
        int e = t + it * 256;
        kept[it] = false;
        if (e < EPG){
            bool k = false;
            if (lm[it]){
                int key = (la[it] - cbase) * GG + (lb[it] - cbase);
                k = (pm[key] == (unsigned)e);
            }
            kept[it] = k;
            if (kf_out) kf_out[e0 + e] = k ? 1 : 0;
            if (k){
                atomicAdd(&degs[lb[it] - cbase], 1.f);
                float c0 = pp[la[it]*2]     - pp[lb[it]*2];
                float c1 = pp[la[it]*2 + 1] - pp[lb[it]*2 + 1];
                cand = fmaxf(cand, fmaxf(fabsf(c0), fabsf(c1)));
            }
        }
    }
    red[t] = cand; __syncthreads();
    for (int o = 128; o > 0; o >>= 1){
        if (t < o) red[t] = fmaxf(red[t], red[t + o]);
        __syncthreads();
    }
    if (t == 0){
        if (red[0] > 0.f) atomicMax(amax, __float_as_uint(red[0]));
        int run = 0;
        for (int i = 0; i < GG; i++){ rs[i] = run; run += (int)degs[i]; }
        rs[GG] = run;
    }
    __syncthreads();
    if (t < GG){
        rowptr2[(cbase + t)*2]     = e0 + rs[t];
        rowptr2[(cbase + t)*2 + 1] = e0 + rs[t + 1];
        cur[t] = rs[t];
    }
    __syncthreads();
    for (int it = 0; it < niter; it++){
        int e = t + it * 256;
        if (kept[it]){
            int slot = atomicAdd(&cur[lb[it] - cbase], 1);
            elist[e0 + slot] = e0 + e;
        }
    }
}

// ---------------- generic mid pooling (stage2), one block per graph ----------------
template<int CIN, int G>
__global__ __launch_bounds__(256) void pool_mid_k(
        const float* __restrict__ xin, const float* __restrict__ ppin,
        const float* __restrict__ svin, float size,
        float* __restrict__ pxout, float* __restrict__ ppout, float* __restrict__ svout,
        int* __restrict__ clout){
    __shared__ unsigned px[G * G * 64];
    __shared__ float cnt[G * G], ps[2 * G * G];
    __shared__ int cli[CIN];
    const int b = blockIdx.x, t = threadIdx.x;

    for (int i = t; i < G * G * 64; i += 256) px[i] = 0u;
    if (t < G * G){ cnt[t] = 0.f; ps[t*2] = 0.f; ps[t*2 + 1] = 0.f; }
    if (t < CIN){
        float v  = svin[b*CIN + t];
        float p0 = ppin[(b*CIN + t)*2], p1 = ppin[(b*CIN + t)*2 + 1];
        int c0 = min(max((int)floorf(p0 / size), 0), G - 1);
        int c1 = min(max((int)floorf(p1 / size), 0), G - 1);
        int c = c1 * G + c0;
        cli[t] = (v > 0.f) ? c : -1;
        clout[b*CIN + t] = b * G * G + c;
    }
    __syncthreads();
    if (t < CIN && cli[t] >= 0){
        int c = cli[t];
        atomicAdd(&cnt[c], 1.f);
        atomicAdd(&ps[c*2],     ppin[(b*CIN + t)*2]);
        atomicAdd(&ps[c*2 + 1], ppin[(b*CIN + t)*2 + 1]);
    }
    __syncthreads();
    for (int idx = t; idx < CIN * 64; idx += 256){
        int i = idx >> 6, f = idx & 63;
        if (cli[i] >= 0)
            atomicMax(&px[cli[i]*64 + f], fenc(xin[(size_t)(b*CIN + i)*64 + f]));
    }
    __syncthreads();
    for (int idx = t; idx < G * G * 64; idx += 256){
        int s_ = idx >> 6;
        pxout[(size_t)(b*G*G)*64 + idx] = (cnt[s_] > 0.f) ? fdec(px[idx]) : 0.f;
    }
    if (t < G * G){
        float c = cnt[t], m = fmaxf(c, 1.f);
        ppout[(b*G*G + t)*2]     = ps[t*2] / m;
        ppout[(b*G*G + t)*2 + 1] = ps[t*2 + 1] / m;
        svout[b*G*G + t] = (c > 0.f) ? 1.f : 0.f;
    }
}

// ---------------- W' = [W ; root] -> fp16, swizzled into MFMA B-fragment order ----------------
// Wswz[((kt*4 + nt)*64 + lane)*8 + j] = Wc[kt*32 + (lane>>4)*8 + j][nt*16 + (lane&15)]
__global__ void wswz_k(const float* __restrict__ W, const float* __restrict__ root,
                       int FIN, _Float16* __restrict__ Wz){
    int gid = blockIdx.x * 256 + threadIdx.x;
    int KT = 26 * FIN;
    if (gid >= KT * 64) return;
    int k = gid >> 6, n = gid & 63;
    float v = (k < 25 * FIN) ? W[(size_t)k * 64 + n] : root[(size_t)(k - 25 * FIN) * 64 + n];
    int kt = k >> 5, kr = k & 31, quad = kr >> 3, j = kr & 7;
    int lane = (quad << 4) | (n & 15);
    int nt = n >> 4;
    Wz[(((size_t)(kt * 4 + nt) * 64 + lane) << 3) + j] = (_Float16)v;
}

// ---------------- conv2/conv3 phase A: CSR gather into LDS, dump A' rows (fp16) ----------------
// A'[node] = [acc/deg (25*FIN) | x[node] (FIN)], stride 26*FIN, fp16.
template<int FIN>
__global__ __launch_bounds__(256) void conv_gather_k(
        const float* __restrict__ x, const float* __restrict__ ppos,
        const int* __restrict__ esrc, const int* __restrict__ elist,
        const int* __restrict__ rowptr2, const unsigned* __restrict__ amaxp,
        int n, _Float16* __restrict__ Aout){
    constexpr int EPB = (FIN == 32) ? 2 : 1;
    constexpr int ACC = 25 * FIN;
    constexpr int KTOT = 26 * FIN;
    __shared__ float acc[4 * EPB * ACC];           // 25.6 KB
    int g = threadIdx.x >> 6, lane = threadIdx.x & 63;
    int node = blockIdx.x * 4 + g;
    float* accg = acc + g * EPB * ACC;

    for (int i = threadIdx.x; i < 4 * EPB * ACC; i += 256) acc[i] = 0.f;
    __syncthreads();

    int row0 = 0, row1 = 0;
    if (node < n){
        row0 = rowptr2[node*2]; row1 = rowptr2[node*2 + 1];
        float am = __uint_as_float(*amaxp);
        float pd0 = ppos[node*2], pd1 = ppos[node*2 + 1];
        int ebuf = (EPB == 2) ? (lane >> 5) : 0;
        int f = lane & (FIN - 1);
        float* ab = accg + ebuf * ACC;
        for (int i = row0 + ebuf; i < row1; i += EPB){
            int e = elist[i];
            int a = esrc[e];
            float c0 = ppos[a*2]     - pd0;
            float c1 = ppos[a*2 + 1] - pd1;
            int kks[4]; float wsp[4];
            spline2(c0, c1, am, kks, wsp);
            float xv = x[(size_t)a * FIN + f];
            #pragma unroll
            for (int c = 0; c < 4; c++) ab[kks[c] * FIN + f] += wsp[c] * xv;
        }
    }
    __syncthreads();

    if (node >= n) return;
    float inv = 1.f / (float)max(row1 - row0, 1);
    _Float16* dstrow = Aout + (size_t)node * KTOT;
    const float4* s4  = (const float4*)accg;
    const float4* s4b = (const float4*)(accg + ACC);
    #pragma unroll 2
    for (int j = lane; j < ACC / 4; j += 64){
        float4 v = s4[j];
        if (EPB == 2){
            float4 u = s4b[j];
            v.x += u.x; v.y += u.y; v.z += u.z; v.w += u.w;
        }
        half4 h;
        h.x = (_Float16)(v.x * inv); h.y = (_Float16)(v.y * inv);
        h.z = (_Float16)(v.z * inv); h.w = (_Float16)(v.w * inv);
        *(half4*)&dstrow[j * 4] = h;
    }
    const float4* x4 = (const float4*)(x + (size_t)node * FIN);
    for (int j = lane; j < FIN / 4; j += 64){
        float4 v = x4[j];
        half4 h;
        h.x = (_Float16)v.x; h.y = (_Float16)v.y;
        h.z = (_Float16)v.z; h.w = (_Float16)v.w;
        *(half4*)&dstrow[ACC + j * 4] = h;
    }
}

// ---------------- conv2/conv3 phase B: MFMA GEMM (fp16 in, fp32 acc), split-K ----------------
// Wave = 16 rows x 64 cols (4 x mfma_f32_16x16x32_f16). Block = 4 waves = 64 rows.
// A-frag: lane reads A'[m0+(lane&15)][kt*32+(lane>>4)*8 .. +7] (16B, row-major fp16).
// B-frag: one coalesced 16B load from pre-swizzled Wswz. No LDS.
template<int KTOT, int SPLITK>
__global__ __launch_bounds__(256) void conv_mfma_k(
        const _Float16* __restrict__ A, const _Float16* __restrict__ Wz,
        int M, float* __restrict__ Cpart){
    constexpr int NSTEP = KTOT / SPLITK / 32;   // 13 for both convs
    const int w = threadIdx.x >> 6, lane = threadIdx.x & 63;
    const int m0 = blockIdx.x * 64 + w * 16;
    const int kt0 = blockIdx.y * NSTEP;
    const int quad = lane >> 4;

    f32x4 acc[4];
    #pragma unroll
    for (int nt = 0; nt < 4; nt++) acc[nt] = (f32x4){0.f, 0.f, 0.f, 0.f};

    const half8* __restrict__ Arow = (const half8*)(A + (size_t)(m0 + (lane & 15)) * KTOT);
    const half8* __restrict__ Wp   = (const half8*)Wz + (size_t)kt0 * 4 * 64 + lane;

    for (int kt = 0; kt < NSTEP; kt++){
        half8 a = Arow[(kt0 + kt) * 4 + quad];
        #pragma unroll
        for (int nt = 0; nt < 4; nt++){
            half8 b = Wp[(kt * 4 + nt) * 64];
            acc[nt] = __builtin_amdgcn_mfma_f32_16x16x32_f16(a, b, acc[nt], 0, 0, 0);
        }
    }

    // C/D layout: col = lane&15, row = quad*4 + reg
    float* cp = Cpart + ((size_t)blockIdx.y * M + m0) * 64;
    const int r = quad * 4, c = lane & 15;
    #pragma unroll
    for (int nt = 0; nt < 4; nt++)
        #pragma unroll
        for (int i = 0; i < 4; i++)
            cp[(size_t)(r + i) * 64 + nt * 16 + c] = acc[nt][i];
}

// ---------------- conv epilogue: combine split-K partials + bias + ELU ----------------
template<int SPLITK>
__global__ void conv_epi_k(const float* __restrict__ Cpart, const float* __restrict__ bias,
                           int M, float* __restrict__ out){
    int gid = blockIdx.x * 256 + threadIdx.x;
    if (gid >= M * 64) return;
    int c = gid & 63;
    float v = bias[c];
    #pragma unroll
    for (int s = 0; s < SPLITK; s++) v += Cpart[(size_t)s * M * 64 + gid];
    out[gid] = eluf(v);
}

// ---------------- final pool (size=14, G=2) + MLP head + log_softmax ----------------
__global__ __launch_bounds__(256) void final_k(
        const float* __restrict__ xin, const float* __restrict__ ppin,
        const float* __restrict__ svin,
        const float* __restrict__ fw1, const float* __restrict__ fb1,
        const float* __restrict__ fw2, const float* __restrict__ fb2,
        float* __restrict__ out){
    __shared__ unsigned px[4 * 64];
    __shared__ float cnt[4];
    __shared__ int cli[25];
    __shared__ float xr[256];
    __shared__ float h[128];
    __shared__ float lg[10];
    __shared__ float lse;
    const int b = blockIdx.x, t = threadIdx.x;

    if (t < 4*64) px[t] = 0u;
    if (t < 4) cnt[t] = 0.f;
    if (t < 25){
        float v  = svin[b*25 + t];
        float p0 = ppin[(b*25 + t)*2], p1 = ppin[(b*25 + t)*2 + 1];
        int c0 = min(max((int)floorf(p0 / 14.f), 0), 1);
        int c1 = min(max((int)floorf(p1 / 14.f), 0), 1);
        int c = c1 * 2 + c0;
        cli[t] = (v > 0.f) ? c : -1;
    }
    __syncthreads();
    if (t < 25 && cli[t] >= 0) atomicAdd(&cnt[cli[t]], 1.f);
    __syncthreads();
    for (int idx = t; idx < 25 * 64; idx += 256){
        int i = idx >> 6, f = idx & 63;
        if (cli[i] >= 0)
            atomicMax(&px[cli[i]*64 + f], fenc(xin[(size_t)(b*25 + i)*64 + f]));
    }
    __syncthreads();
    xr[t] = (cnt[t >> 6] > 0.f) ? fdec(px[t]) : 0.f;
    __syncthreads();
    if (t < 128){
        float s = fb1[t];
        const float* wrow = fw1 + (size_t)t * 256;
        #pragma unroll 8
        for (int i = 0; i < 256; i++) s += xr[i] * wrow[i];
        h[t] = eluf(s);
    }
    __syncthreads();
    if (t < 10){
        float s2 = fb2[t];
        const float* w2 = fw2 + (size_t)t * 128;
        for (int j = 0; j < 128; j++) s2 += h[j] * w2[j];
        lg[t] = s2;
    }
    __syncthreads();
    if (t == 0){
        float m = lg[0];
        for (int c = 1; c < 10; c++) m = fmaxf(m, lg[c]);
        float se = 0.f;
        for (int c = 0; c < 10; c++) se += expf(lg[c] - m);
        lse = m + logf(se);
    }
    __syncthreads();
    if (t < 10) out[(size_t)b*10 + t] = lg[t] - lse;
}

extern "C" void kernel_launch(void* const* d_in, const int* in_sizes, int n_in,
                              void* d_out, int out_size, void* d_ws, size_t ws_size,
                              hipStream_t stream) {
    const float* x   = (const float*)d_in[0];
    const float* pos = (const float*)d_in[1];
    const int*   src = (const int*)d_in[2];
    const int*   dst = (const int*)d_in[3];
    const float* W1  = (const float*)d_in[4];
    const float* r1  = (const float*)d_in[5];
    const float* b1  = (const float*)d_in[6];
    const float* W2  = (const float*)d_in[7];
    const float* r2  = (const float*)d_in[8];
    const float* b2  = (const float*)d_in[9];
    const float* W3  = (const float*)d_in[10];
    const float* r3  = (const float*)d_in[11];
    const float* b3  = (const float*)d_in[12];
    const float* fw1 = (const float*)d_in[13];
    const float* fb1 = (const float*)d_in[14];
    const float* fw2 = (const float*)d_in[15];
    const float* fb2 = (const float*)d_in[16];
    float* out = (float*)d_out;

    const int N   = in_sizes[0];
    const int E   = in_sizes[2];
    const int B   = N / NPG;
    const int EPG = E / B;
    const int S1  = B * 36;
    const int S2  = B * 25;

    float* w = (float*)d_ws;
    size_t off = 0;
    auto alloc = [&](size_t nelem){ size_t o = off; off += (nelem + 63) & ~(size_t)63; return o; };

    size_t o_scal = alloc(4);                 // amax0, amax1, amax2 — only memset needed
    size_t o_px1  = alloc((size_t)S1 * 32);
    size_t o_pp1  = alloc((size_t)S1 * 2);
    size_t o_sv1  = alloc(S1);
    size_t o_cl1  = alloc(N);
    size_t o_kf1  = alloc((E + 3) / 4);
    size_t o_es1  = alloc(E);
    size_t o_ed1  = alloc(E);
    size_t o_el   = alloc(E);
    size_t o_rp2  = alloc((size_t)2 * S1);
    size_t o_rp3  = alloc((size_t)2 * S2);
    size_t o_out2 = alloc((size_t)S1 * 64);
    size_t o_cl2  = alloc(S1);
    size_t o_px2  = alloc((size_t)S2 * 64);
    size_t o_pp2  = alloc((size_t)S2 * 2);
    size_t o_sv2  = alloc(S2);
    size_t o_out3 = alloc((size_t)S2 * 64);
    size_t o_wz   = alloc((size_t)26 * 64 * 64 / 2 + 64);          // fp16 swizzled W' (max 1664*64 halfs)
    size_t cpElems = (size_t)2 * S1 * 64 > (size_t)4 * S2 * 64 ? (size_t)2 * S1 * 64 : (size_t)4 * S2 * 64;
    size_t o_cp   = alloc(cpElems);           // split-K fp32 partials (union of conv2/conv3)
    // A' fp16 scratch (union: conv2 S1*832, conv3 S2*1664 halfs; sequential use)
    size_t accAhalfs = (size_t)S1 * 832 > (size_t)S2 * 1664 ? (size_t)S1 * 832 : (size_t)S2 * 1664;
    size_t o_accA = alloc((accAhalfs + 1) / 2);

    hipMemsetAsync(w + o_scal, 0, 4 * sizeof(float), stream);

    unsigned* scal = (unsigned*)(w + o_scal);
    _Float16* Wz   = (_Float16*)(w + o_wz);
    _Float16* A16  = (_Float16*)(w + o_accA);
    auto nb = [](long long t){ return (unsigned)((t + 255) / 256); };
    auto nb4 = [](long long t){ return (unsigned)((t + 3) / 4); };

    // stage 1: amax over original edges, then fused conv1+pool1 per graph
    amax0_k<<<nb(E), 256, 0, stream>>>(pos, src, dst, E, scal + 0);
    conv1pool1_k<<<B, 256, 0, stream>>>(x, pos, src, dst, EPG, scal + 0, W1, r1, b1,
                                        w + o_px1, w + o_pp1, w + o_sv1, (int*)(w + o_cl1));

    // stage-1 -> stage-2 graph: fused dedup + CSR per graph
    dedup_csr_k<36><<<B, 256, 0, stream>>>(
        src, dst, (int*)(w + o_cl1), nullptr,
        (unsigned char*)(w + o_kf1), (int*)(w + o_es1), (int*)(w + o_ed1),
        w + o_pp1, EPG, (int*)(w + o_el), (int*)(w + o_rp2), scal + 1);

    // conv2 (Fin=32 -> 64), MFMA, split-K = 2
    wswz_k<<<nb(26 * 32 * 64), 256, 0, stream>>>(W2, r2, 32, Wz);
    conv_gather_k<32><<<nb4(S1), 256, 0, stream>>>(
        w + o_px1, w + o_pp1, (int*)(w + o_es1), (int*)(w + o_el), (int*)(w + o_rp2),
        scal + 1, S1, A16);
    {
        dim3 g(S1 / 64, 2);
        conv_mfma_k<832, 2><<<g, 256, 0, stream>>>(A16, Wz, S1, w + o_cp);
    }
    conv_epi_k<2><<<nb((long long)S1 * 64), 256, 0, stream>>>(w + o_cp, b2, S1, w + o_out2);

    // pool 2 (size=7, G=5)
    pool_mid_k<36, 5><<<B, 256, 0, stream>>>(
        w + o_out2, w + o_pp1, w + o_sv1, 7.f,
        w + o_px2, w + o_pp2, w + o_sv2, (int*)(w + o_cl2));

    // stage-2 -> stage-3 graph (in-place remap of es1/ed1)
    dedup_csr_k<25><<<B, 256, 0, stream>>>(
        (int*)(w + o_es1), (int*)(w + o_ed1), (int*)(w + o_cl2), (unsigned char*)(w + o_kf1),
        nullptr, (int*)(w + o_es1), (int*)(w + o_ed1),
        w + o_pp2, EPG, (int*)(w + o_el), (int*)(w + o_rp3), scal + 2);

    // conv3 (Fin=64 -> 64), MFMA, split-K = 4
    wswz_k<<<nb(26 * 64 * 64), 256, 0, stream>>>(W3, r3, 64, Wz);
    conv_gather_k<64><<<nb4(S2), 256, 0, stream>>>(
        w + o_px2, w + o_pp2, (int*)(w + o_es1), (int*)(w + o_el), (int*)(w + o_rp3),
        scal + 2, S2, A16);
    {
        dim3 g(S2 / 64, 4);
        conv_mfma_k<1664, 4><<<g, 256, 0, stream>>>(A16, Wz, S2, w + o_cp);
    }
    conv_epi_k<4><<<nb((long long)S2 * 64), 256, 0, stream>>>(w + o_cp, b3, S2, w + o_out3);

    // final pool + MLP + log_softmax, per graph
    final_k<<<B, 256, 0, stream>>>(w + o_out3, w + o_pp2, w + o_sv2,
                                   fw1, fb1, fw2, fb2, out);
}